// Round 1
// baseline (1687.589 us; speedup 1.0000x reference)
//
#include <hip/hip_runtime.h>

#define DINc 64
#define DHc  128
#define DEc  16
#define Gc   256
#define Rrep 64

// ---------------- edge pass: aggr[dst] += relu(x[src] + ea @ ewT + eb) ----------------
template<int D>
__global__ __launch_bounds__(256) void edge_conv(
    const float* __restrict__ xin, const int* __restrict__ srcA, const int* __restrict__ dstA,
    const float* __restrict__ ea, const float* __restrict__ ew, const float* __restrict__ eb,
    float* __restrict__ aggr, const int nE)
{
  constexpr int SL = 256 / D;              // edges per block-iteration
  __shared__ float ewT[DEc * D];           // [k][d]
  __shared__ float ebs[D];
  __shared__ float eas[SL][DEc];
  __shared__ int   ssrc[SL], sdst[SL];
  const int tid = threadIdx.x;
  for (int t = tid; t < DEc * D; t += 256) {
    int dd = t / DEc, k = t % DEc;
    ewT[k * D + dd] = ew[t];               // ew is [D][DEc] row-major
  }
  if (tid < D) ebs[tid] = eb[tid];
  const int d  = tid % D;
  const int sl = tid / D;
  const int stride = gridDim.x * SL;
  for (int base = blockIdx.x * SL; base < nE; base += stride) {
    __syncthreads();
    if (tid < SL * DEc) {
      int e = base + tid / DEc;
      eas[tid / DEc][tid % DEc] = (e < nE) ? ea[e * DEc + (tid % DEc)] : 0.f;
    }
    if (tid < SL) {
      int e = base + tid;
      ssrc[tid] = (e < nE) ? srcA[e] : 0;
      sdst[tid] = (e < nE) ? dstA[e] : 0;
    }
    __syncthreads();
    int e = base + sl;
    if (e < nE) {
      float v = ebs[d];
      #pragma unroll
      for (int k = 0; k < DEc; ++k) v = fmaf(eas[sl][k], ewT[k * D + d], v);
      float m = xin[ssrc[sl] * D + d] + v;
      m = fmaxf(m, 0.f);
      atomicAdd(&aggr[sdst[sl] * D + d], m);
    }
  }
}

// ---------------- node MLP: out = relu( relu((x+aggr)@waT+ba) @ wbT + bb ) ----------------
// blockDim 512 = 8 waves; each wave owns 4 nodes; each thread: 2 nodes x 4 consecutive j.
template<int IN, bool FINAL>
__global__ __launch_bounds__(512) void mlp_node(
    const float* __restrict__ xin, const float* __restrict__ aggr,
    const float* __restrict__ wa, const float* __restrict__ ba,
    const float* __restrict__ wb, const float* __restrict__ bb,
    float* __restrict__ hout,
    const int* __restrict__ batch,
    float* __restrict__ sums, float* __restrict__ cnts,
    const int nN)
{
  __shared__ __align__(16) float waT[IN * DHc];   // [i][j]
  __shared__ __align__(16) float wbT[DHc * DHc];  // [k][j]
  __shared__ __align__(16) float tbuf[32][DHc];   // wave-private node rows (in, then t)
  const int tid = threadIdx.x;
  for (int t = tid; t < IN * DHc; t += 512) { int j = t / IN, i = t % IN; waT[i * DHc + j] = wa[t]; }
  for (int t = tid; t < DHc * DHc; t += 512) { int j = t >> 7, k = t & 127; wbT[k * DHc + j] = wb[t]; }
  const int lane = tid & 63;
  const int wv   = tid >> 6;
  const int jg   = lane & 31;
  const int j0   = jg * 4;
  const int p    = lane >> 5;
  const float4 ba4 = *(const float4*)(ba + j0);
  const float4 bb4 = *(const float4*)(bb + j0);
  const float4* waT4 = (const float4*)waT;
  const float4* wbT4 = (const float4*)wbT;
  const int rep = blockIdx.x & (Rrep - 1);
  __syncthreads();
  for (int base = blockIdx.x * 32; base < nN; base += gridDim.x * 32) {
    // stage this wave's 4 node inputs (wave-private rows -> no block barrier needed)
    for (int t = lane; t < 4 * IN; t += 64) {
      int s = t / IN, i = t % IN;
      int n = base + wv * 4 + s;
      tbuf[wv * 4 + s][i] = (n < nN) ? xin[n * IN + i] + aggr[n * IN + i] : 0.f;
    }
    const int s0 = wv * 4 + p * 2;
    const int s1 = s0 + 1;
    // layer 1
    float4 a0 = ba4, a1 = ba4;
    #pragma unroll 8
    for (int i = 0; i < IN; ++i) {
      float x0 = tbuf[s0][i], x1 = tbuf[s1][i];
      float4 w = waT4[i * 32 + jg];
      a0.x = fmaf(x0, w.x, a0.x); a0.y = fmaf(x0, w.y, a0.y);
      a0.z = fmaf(x0, w.z, a0.z); a0.w = fmaf(x0, w.w, a0.w);
      a1.x = fmaf(x1, w.x, a1.x); a1.y = fmaf(x1, w.y, a1.y);
      a1.z = fmaf(x1, w.z, a1.z); a1.w = fmaf(x1, w.w, a1.w);
    }
    float4 t0, t1;
    t0.x = fmaxf(a0.x, 0.f); t0.y = fmaxf(a0.y, 0.f); t0.z = fmaxf(a0.z, 0.f); t0.w = fmaxf(a0.w, 0.f);
    t1.x = fmaxf(a1.x, 0.f); t1.y = fmaxf(a1.y, 0.f); t1.z = fmaxf(a1.z, 0.f); t1.w = fmaxf(a1.w, 0.f);
    *(float4*)(&tbuf[s0][j0]) = t0;
    *(float4*)(&tbuf[s1][j0]) = t1;
    // layer 2
    float4 c0 = bb4, c1 = bb4;
    #pragma unroll 8
    for (int k = 0; k < DHc; ++k) {
      float y0 = tbuf[s0][k], y1 = tbuf[s1][k];
      float4 w = wbT4[k * 32 + jg];
      c0.x = fmaf(y0, w.x, c0.x); c0.y = fmaf(y0, w.y, c0.y);
      c0.z = fmaf(y0, w.z, c0.z); c0.w = fmaf(y0, w.w, c0.w);
      c1.x = fmaf(y1, w.x, c1.x); c1.y = fmaf(y1, w.y, c1.y);
      c1.z = fmaf(y1, w.z, c1.z); c1.w = fmaf(y1, w.w, c1.w);
    }
    float4 o0, o1;   // post-conv relu (reference applies relu after each conv)
    o0.x = fmaxf(c0.x, 0.f); o0.y = fmaxf(c0.y, 0.f); o0.z = fmaxf(c0.z, 0.f); o0.w = fmaxf(c0.w, 0.f);
    o1.x = fmaxf(c1.x, 0.f); o1.y = fmaxf(c1.y, 0.f); o1.z = fmaxf(c1.z, 0.f); o1.w = fmaxf(c1.w, 0.f);
    const int na = base + s0, nb = base + s1;
    const bool n0v = na < nN, n1v = nb < nN;
    if (!FINAL) {
      if (n0v) *(float4*)(hout + na * DHc + j0) = o0;
      if (n1v) *(float4*)(hout + nb * DHc + j0) = o1;
    } else {
      int ga = batch[n0v ? na : (nN - 1)];
      int gb = batch[n1v ? nb : (nN - 1)];
      int gref = __shfl(ga, 0);
      bool all4 = (base + wv * 4 + 3) < nN;
      bool uni = __all((ga == gref) && (gb == gref)) && all4;
      if (uni) {
        float4 s4;
        s4.x = o0.x + o1.x; s4.y = o0.y + o1.y; s4.z = o0.z + o1.z; s4.w = o0.w + o1.w;
        s4.x += __shfl_xor(s4.x, 32); s4.y += __shfl_xor(s4.y, 32);
        s4.z += __shfl_xor(s4.z, 32); s4.w += __shfl_xor(s4.w, 32);
        if (p == 0) {
          float* dp = sums + ((size_t)rep * Gc + gref) * DHc + j0;
          atomicAdd(dp + 0, s4.x); atomicAdd(dp + 1, s4.y);
          atomicAdd(dp + 2, s4.z); atomicAdd(dp + 3, s4.w);
        }
        if (lane == 0) atomicAdd(cnts + rep * Gc + gref, 4.f);
      } else {
        if (n0v) {
          float* dp = sums + ((size_t)rep * Gc + ga) * DHc + j0;
          atomicAdd(dp + 0, o0.x); atomicAdd(dp + 1, o0.y);
          atomicAdd(dp + 2, o0.z); atomicAdd(dp + 3, o0.w);
        }
        if (n1v) {
          float* dp = sums + ((size_t)rep * Gc + gb) * DHc + j0;
          atomicAdd(dp + 0, o1.x); atomicAdd(dp + 1, o1.y);
          atomicAdd(dp + 2, o1.z); atomicAdd(dp + 3, o1.w);
        }
        if (jg == 0) {
          if (n0v) atomicAdd(cnts + rep * Gc + ga, 1.f);
          if (n1v) atomicAdd(cnts + rep * Gc + gb, 1.f);
        }
      }
    }
  }
}

// ---------------- final: reduce replicas, mean, dot with wf ----------------
__global__ __launch_bounds__(128) void pool_final(
    const float* __restrict__ sums, const float* __restrict__ cnts,
    const float* __restrict__ wf, const float* __restrict__ bf,
    float* __restrict__ out)
{
  const int g = blockIdx.x;
  const int j = threadIdx.x;
  __shared__ float red[128];
  float s = 0.f;
  for (int r = 0; r < Rrep; ++r) s += sums[((size_t)r * Gc + g) * DHc + j];
  float c = (j < Rrep) ? cnts[j * Gc + g] : 0.f;
  red[j] = c;
  __syncthreads();
  for (int off = 64; off > 0; off >>= 1) { if (j < off) red[j] += red[j + off]; __syncthreads(); }
  float ct = fmaxf(red[0], 1.f);
  __syncthreads();
  red[j] = (s / ct) * wf[j];
  __syncthreads();
  for (int off = 64; off > 0; off >>= 1) { if (j < off) red[j] += red[j + off]; __syncthreads(); }
  if (j == 0) out[g] = red[0] + bf[0];
}

extern "C" void kernel_launch(void* const* d_in, const int* in_sizes, int n_in,
                              void* d_out, int out_size, void* d_ws, size_t ws_size,
                              hipStream_t stream) {
  const float* x    = (const float*)d_in[0];
  const int*   ei   = (const int*)d_in[1];
  const float* ea   = (const float*)d_in[2];
  const int*   batch= (const int*)d_in[3];
  const float* ew1  = (const float*)d_in[4];
  const float* eb1  = (const float*)d_in[5];
  const float* w1a  = (const float*)d_in[6];
  const float* b1a  = (const float*)d_in[7];
  const float* w1b  = (const float*)d_in[8];
  const float* b1b  = (const float*)d_in[9];
  const float* ew2  = (const float*)d_in[10];
  const float* eb2  = (const float*)d_in[11];
  const float* w2a  = (const float*)d_in[12];
  const float* b2a  = (const float*)d_in[13];
  const float* w2b  = (const float*)d_in[14];
  const float* b2b  = (const float*)d_in[15];
  const float* wf   = (const float*)d_in[16];
  const float* bf   = (const float*)d_in[17];
  float* out = (float*)d_out;

  const int nN = in_sizes[0] / DINc;
  const int nE = in_sizes[1] / 2;
  const int* srcA = ei;
  const int* dstA = ei + nE;

  char* wsb = (char*)d_ws;
  float* h1   = (float*)(wsb);
  float* aggr = (float*)(wsb + (size_t)nN * DHc * 4);
  float* sums = (float*)(wsb + (size_t)nN * DHc * 4 * 2);
  float* cnts = (float*)(wsb + (size_t)nN * DHc * 4 * 2 + (size_t)Rrep * Gc * DHc * 4);
  (void)ws_size; (void)n_in; (void)out_size;

  // zero aggregation buffers (stream-ordered)
  hipMemsetAsync(aggr, 0, (size_t)nN * DINc * 4, stream);
  hipMemsetAsync(sums, 0, (size_t)Rrep * Gc * DHc * 4 + (size_t)Rrep * Gc * 4, stream);

  edge_conv<DINc><<<32768, 256, 0, stream>>>(x, srcA, dstA, ea, ew1, eb1, aggr, nE);

  const int mgrid = (nN + 31) / 32;
  mlp_node<DINc, false><<<mgrid, 512, 0, stream>>>(x, aggr, w1a, b1a, w1b, b1b,
                                                   h1, nullptr, nullptr, nullptr, nN);

  hipMemsetAsync(aggr, 0, (size_t)nN * DHc * 4, stream);

  edge_conv<DHc><<<32768, 256, 0, stream>>>(h1, srcA, dstA, ea, ew2, eb2, aggr, nE);

  mlp_node<DHc, true><<<mgrid, 512, 0, stream>>>(h1, aggr, w2a, b2a, w2b, b2b,
                                                 nullptr, batch, sums, cnts, nN);

  pool_final<<<Gc, 128, 0, stream>>>(sums, cnts, wf, bf, out);
}

// Round 2
// 1484.811 us; speedup vs baseline: 1.1366x; 1.1366x over previous
//
#include <hip/hip_runtime.h>

#define DINc 64
#define DHc  128
#define DEc  16
#define Gc   256
#define Rrep 64

// ---------------- CSR build ----------------
__global__ __launch_bounds__(256) void k_hist(const int* __restrict__ dstA, const int nE,
                                              int* __restrict__ deg) {
  for (int i = blockIdx.x * 256 + threadIdx.x; i < nE; i += gridDim.x * 256)
    atomicAdd(&deg[dstA[i]], 1);
}

__global__ __launch_bounds__(1024) void k_scan(const int* __restrict__ deg,
                                               int* __restrict__ rowptr, const int nN) {
  __shared__ int part[1024];
  const int t = threadIdx.x;
  const int C = (nN + 1023) >> 10;
  const int b = min(t * C, nN), e = min(b + C, nN);
  int s = 0;
  for (int i = b; i < e; ++i) s += deg[i];
  part[t] = s;
  __syncthreads();
  for (int off = 1; off < 1024; off <<= 1) {
    int u = (t >= off) ? part[t - off] : 0;
    __syncthreads();
    part[t] += u;
    __syncthreads();
  }
  int run = part[t] - s;          // exclusive prefix for this thread's chunk
  const int total = part[1023];
  for (int i = b; i < e; ++i) { rowptr[i] = run; run += deg[i]; }
  if (t == 1023) rowptr[nN] = total;
}

__global__ __launch_bounds__(256) void k_fill(const int* __restrict__ dstA, const int nE,
                                              const int* __restrict__ rowptr,
                                              int* __restrict__ cursor, int* __restrict__ eidx) {
  for (int i = blockIdx.x * 256 + threadIdx.x; i < nE; i += gridDim.x * 256) {
    const int d = dstA[i];
    const int pos = atomicAdd(&cursor[d], 1);
    eidx[rowptr[d] + pos] = i;
  }
}

// ---------------- gather aggregation: aggr[n] = sum_{e: dst=n} relu(x[src]+ea@ewT+eb) ----------------
// one wave per node; lanes cover D; 64-edge id batches broadcast via shfl.
template<int D>
__global__ __launch_bounds__(256) void gather_conv(
    const float* __restrict__ xin, const int* __restrict__ srcA,
    const float* __restrict__ ea, const float* __restrict__ ew,
    const float* __restrict__ eb, const int* __restrict__ rowptr,
    const int* __restrict__ eidx, float* __restrict__ aggr, const int nN)
{
  constexpr int PL = D / 64;               // floats per lane
  const int lane = threadIdx.x & 63;
  const int wv   = threadIdx.x >> 6;
  float wreg[16 * PL];
  float ebr[PL];
  #pragma unroll
  for (int p = 0; p < PL; ++p) {
    const int d = lane * PL + p;
    ebr[p] = eb[d];
    #pragma unroll
    for (int k = 0; k < 16; ++k) wreg[k * PL + p] = ew[d * 16 + k];  // ew is [D][16]
  }
  const float4* __restrict__ ea4 = (const float4*)ea;
  const int gw = blockIdx.x * 4 + wv;
  const int nw = gridDim.x * 4;
  for (int n = gw; n < nN; n += nw) {
    const int beg = rowptr[n], end = rowptr[n + 1];
    float acc[PL];
    #pragma unroll
    for (int p = 0; p < PL; ++p) acc[p] = 0.f;
    for (int chunk = beg; chunk < end; chunk += 64) {
      const int cnt = min(64, end - chunk);
      const int eL = (lane < cnt) ? eidx[chunk + lane] : 0;
      const int sL = (lane < cnt) ? srcA[eL] : 0;
      for (int i = 0; i < cnt; ++i) {
        const int e = __shfl(eL, i);
        const int s = __shfl(sL, i);
        float eav[16];
        *(float4*)(eav + 0)  = ea4[e * 4 + 0];
        *(float4*)(eav + 4)  = ea4[e * 4 + 1];
        *(float4*)(eav + 8)  = ea4[e * 4 + 2];
        *(float4*)(eav + 12) = ea4[e * 4 + 3];
        if (PL == 1) {
          const float xv = xin[s * D + lane];
          float v = ebr[0];
          #pragma unroll
          for (int k = 0; k < 16; ++k) v = fmaf(eav[k], wreg[k], v);
          acc[0] += fmaxf(xv + v, 0.f);
        } else {
          const float2 xv = *(const float2*)(xin + (size_t)s * D + lane * 2);
          float v0 = ebr[0], v1 = ebr[1];
          #pragma unroll
          for (int k = 0; k < 16; ++k) {
            v0 = fmaf(eav[k], wreg[k * 2 + 0], v0);
            v1 = fmaf(eav[k], wreg[k * 2 + 1], v1);
          }
          acc[0] += fmaxf(xv.x + v0, 0.f);
          acc[1] += fmaxf(xv.y + v1, 0.f);
        }
      }
    }
    if (PL == 1) aggr[(size_t)n * D + lane] = acc[0];
    else *(float2*)(aggr + (size_t)n * D + lane * 2) = make_float2(acc[0], acc[1]);
  }
}

// ---------------- node MLP: out = relu( relu((x+aggr)@waT+ba) @ wbT + bb ) ----------------
template<int IN, bool FINAL>
__global__ __launch_bounds__(512) void mlp_node(
    const float* __restrict__ xin, const float* __restrict__ aggr,
    const float* __restrict__ wa, const float* __restrict__ ba,
    const float* __restrict__ wb, const float* __restrict__ bb,
    float* __restrict__ hout,
    const int* __restrict__ batch,
    float* __restrict__ sums, float* __restrict__ cnts,
    const int nN)
{
  __shared__ __align__(16) float waT[IN * DHc];   // [i][j]
  __shared__ __align__(16) float wbT[DHc * DHc];  // [k][j]
  __shared__ __align__(16) float tbuf[32][DHc];   // wave-private node rows
  const int tid = threadIdx.x;
  for (int t = tid; t < IN * DHc; t += 512) { int j = t / IN, i = t % IN; waT[i * DHc + j] = wa[t]; }
  for (int t = tid; t < DHc * DHc; t += 512) { int j = t >> 7, k = t & 127; wbT[k * DHc + j] = wb[t]; }
  const int lane = tid & 63;
  const int wv   = tid >> 6;
  const int jg   = lane & 31;
  const int j0   = jg * 4;
  const int p    = lane >> 5;
  const float4 ba4 = *(const float4*)(ba + j0);
  const float4 bb4 = *(const float4*)(bb + j0);
  const float4* waT4 = (const float4*)waT;
  const float4* wbT4 = (const float4*)wbT;
  const int rep = blockIdx.x & (Rrep - 1);
  __syncthreads();
  for (int base = blockIdx.x * 32; base < nN; base += gridDim.x * 32) {
    for (int t = lane; t < 4 * IN; t += 64) {
      int s = t / IN, i = t % IN;
      int n = base + wv * 4 + s;
      tbuf[wv * 4 + s][i] = (n < nN) ? xin[n * IN + i] + aggr[n * IN + i] : 0.f;
    }
    const int s0 = wv * 4 + p * 2;
    const int s1 = s0 + 1;
    float4 a0 = ba4, a1 = ba4;
    #pragma unroll 8
    for (int i = 0; i < IN; ++i) {
      float x0 = tbuf[s0][i], x1 = tbuf[s1][i];
      float4 w = waT4[i * 32 + jg];
      a0.x = fmaf(x0, w.x, a0.x); a0.y = fmaf(x0, w.y, a0.y);
      a0.z = fmaf(x0, w.z, a0.z); a0.w = fmaf(x0, w.w, a0.w);
      a1.x = fmaf(x1, w.x, a1.x); a1.y = fmaf(x1, w.y, a1.y);
      a1.z = fmaf(x1, w.z, a1.z); a1.w = fmaf(x1, w.w, a1.w);
    }
    float4 t0, t1;
    t0.x = fmaxf(a0.x, 0.f); t0.y = fmaxf(a0.y, 0.f); t0.z = fmaxf(a0.z, 0.f); t0.w = fmaxf(a0.w, 0.f);
    t1.x = fmaxf(a1.x, 0.f); t1.y = fmaxf(a1.y, 0.f); t1.z = fmaxf(a1.z, 0.f); t1.w = fmaxf(a1.w, 0.f);
    *(float4*)(&tbuf[s0][j0]) = t0;
    *(float4*)(&tbuf[s1][j0]) = t1;
    float4 c0 = bb4, c1 = bb4;
    #pragma unroll 8
    for (int k = 0; k < DHc; ++k) {
      float y0 = tbuf[s0][k], y1 = tbuf[s1][k];
      float4 w = wbT4[k * 32 + jg];
      c0.x = fmaf(y0, w.x, c0.x); c0.y = fmaf(y0, w.y, c0.y);
      c0.z = fmaf(y0, w.z, c0.z); c0.w = fmaf(y0, w.w, c0.w);
      c1.x = fmaf(y1, w.x, c1.x); c1.y = fmaf(y1, w.y, c1.y);
      c1.z = fmaf(y1, w.z, c1.z); c1.w = fmaf(y1, w.w, c1.w);
    }
    float4 o0, o1;
    o0.x = fmaxf(c0.x, 0.f); o0.y = fmaxf(c0.y, 0.f); o0.z = fmaxf(c0.z, 0.f); o0.w = fmaxf(c0.w, 0.f);
    o1.x = fmaxf(c1.x, 0.f); o1.y = fmaxf(c1.y, 0.f); o1.z = fmaxf(c1.z, 0.f); o1.w = fmaxf(c1.w, 0.f);
    const int na = base + s0, nb = base + s1;
    const bool n0v = na < nN, n1v = nb < nN;
    if (!FINAL) {
      if (n0v) *(float4*)(hout + na * DHc + j0) = o0;
      if (n1v) *(float4*)(hout + nb * DHc + j0) = o1;
    } else {
      int ga = batch[n0v ? na : (nN - 1)];
      int gb = batch[n1v ? nb : (nN - 1)];
      int gref = __shfl(ga, 0);
      bool all4 = (base + wv * 4 + 3) < nN;
      bool uni = __all((ga == gref) && (gb == gref)) && all4;
      if (uni) {
        float4 s4;
        s4.x = o0.x + o1.x; s4.y = o0.y + o1.y; s4.z = o0.z + o1.z; s4.w = o0.w + o1.w;
        s4.x += __shfl_xor(s4.x, 32); s4.y += __shfl_xor(s4.y, 32);
        s4.z += __shfl_xor(s4.z, 32); s4.w += __shfl_xor(s4.w, 32);
        if (p == 0) {
          float* dp = sums + ((size_t)rep * Gc + gref) * DHc + j0;
          atomicAdd(dp + 0, s4.x); atomicAdd(dp + 1, s4.y);
          atomicAdd(dp + 2, s4.z); atomicAdd(dp + 3, s4.w);
        }
        if (lane == 0) atomicAdd(cnts + rep * Gc + gref, 4.f);
      } else {
        if (n0v) {
          float* dp = sums + ((size_t)rep * Gc + ga) * DHc + j0;
          atomicAdd(dp + 0, o0.x); atomicAdd(dp + 1, o0.y);
          atomicAdd(dp + 2, o0.z); atomicAdd(dp + 3, o0.w);
        }
        if (n1v) {
          float* dp = sums + ((size_t)rep * Gc + gb) * DHc + j0;
          atomicAdd(dp + 0, o1.x); atomicAdd(dp + 1, o1.y);
          atomicAdd(dp + 2, o1.z); atomicAdd(dp + 3, o1.w);
        }
        if (jg == 0) {
          if (n0v) atomicAdd(cnts + rep * Gc + ga, 1.f);
          if (n1v) atomicAdd(cnts + rep * Gc + gb, 1.f);
        }
      }
    }
  }
}

// ---------------- final: reduce replicas, mean, dot with wf ----------------
__global__ __launch_bounds__(128) void pool_final(
    const float* __restrict__ sums, const float* __restrict__ cnts,
    const float* __restrict__ wf, const float* __restrict__ bf,
    float* __restrict__ out)
{
  const int g = blockIdx.x;
  const int j = threadIdx.x;
  __shared__ float red[128];
  float s = 0.f;
  for (int r = 0; r < Rrep; ++r) s += sums[((size_t)r * Gc + g) * DHc + j];
  float c = (j < Rrep) ? cnts[j * Gc + g] : 0.f;
  red[j] = c;
  __syncthreads();
  for (int off = 64; off > 0; off >>= 1) { if (j < off) red[j] += red[j + off]; __syncthreads(); }
  float ct = fmaxf(red[0], 1.f);
  __syncthreads();
  red[j] = (s / ct) * wf[j];
  __syncthreads();
  for (int off = 64; off > 0; off >>= 1) { if (j < off) red[j] += red[j + off]; __syncthreads(); }
  if (j == 0) out[g] = red[0] + bf[0];
}

extern "C" void kernel_launch(void* const* d_in, const int* in_sizes, int n_in,
                              void* d_out, int out_size, void* d_ws, size_t ws_size,
                              hipStream_t stream) {
  const float* x    = (const float*)d_in[0];
  const int*   ei   = (const int*)d_in[1];
  const float* ea   = (const float*)d_in[2];
  const int*   batch= (const int*)d_in[3];
  const float* ew1  = (const float*)d_in[4];
  const float* eb1  = (const float*)d_in[5];
  const float* w1a  = (const float*)d_in[6];
  const float* b1a  = (const float*)d_in[7];
  const float* w1b  = (const float*)d_in[8];
  const float* b1b  = (const float*)d_in[9];
  const float* ew2  = (const float*)d_in[10];
  const float* eb2  = (const float*)d_in[11];
  const float* w2a  = (const float*)d_in[12];
  const float* b2a  = (const float*)d_in[13];
  const float* w2b  = (const float*)d_in[14];
  const float* b2b  = (const float*)d_in[15];
  const float* wf   = (const float*)d_in[16];
  const float* bf   = (const float*)d_in[17];
  float* out = (float*)d_out;

  const int nN = in_sizes[0] / DINc;
  const int nE = in_sizes[1] / 2;
  const int* srcA = ei;
  const int* dstA = ei + nE;

  char* wsb = (char*)d_ws;
  size_t o = 0;
  float* h1     = (float*)(wsb + o); o += (size_t)nN * DHc * 4;
  float* aggr   = (float*)(wsb + o); o += (size_t)nN * DHc * 4;
  float* sums   = (float*)(wsb + o); o += (size_t)Rrep * Gc * DHc * 4;
  float* cnts   = (float*)(wsb + o); o += (size_t)Rrep * Gc * 4;
  int*   deg    = (int*)  (wsb + o); o += (size_t)nN * 4;
  int*   cursor = (int*)  (wsb + o); o += (size_t)nN * 4;
  int*   rowptr = (int*)  (wsb + o); o += (size_t)(nN + 1) * 4;
  int*   eidx   = (int*)  (wsb + o); o += (size_t)nE * 4;
  (void)ws_size; (void)n_in; (void)out_size;

  // zero: deg+cursor (contiguous), sums+cnts (contiguous)
  hipMemsetAsync(deg, 0, (size_t)nN * 4 * 2, stream);
  hipMemsetAsync(sums, 0, (size_t)Rrep * Gc * DHc * 4 + (size_t)Rrep * Gc * 4, stream);

  // CSR build (reused by both layers)
  k_hist<<<1024, 256, 0, stream>>>(dstA, nE, deg);
  k_scan<<<1, 1024, 0, stream>>>(deg, rowptr, nN);
  k_fill<<<1024, 256, 0, stream>>>(dstA, nE, rowptr, cursor, eidx);

  // layer 1
  gather_conv<DINc><<<2048, 256, 0, stream>>>(x, srcA, ea, ew1, eb1, rowptr, eidx, aggr, nN);
  const int mgrid = (nN + 31) / 32;
  mlp_node<DINc, false><<<mgrid, 512, 0, stream>>>(x, aggr, w1a, b1a, w1b, b1b,
                                                   h1, nullptr, nullptr, nullptr, nN);
  // layer 2
  gather_conv<DHc><<<2048, 256, 0, stream>>>(h1, srcA, ea, ew2, eb2, rowptr, eidx, aggr, nN);
  mlp_node<DHc, true><<<mgrid, 512, 0, stream>>>(h1, aggr, w2a, b2a, w2b, b2b,
                                                 nullptr, batch, sums, cnts, nN);

  pool_final<<<Gc, 128, 0, stream>>>(sums, cnts, wf, bf, out);
}

// Round 3
// 1145.277 us; speedup vs baseline: 1.4735x; 1.2965x over previous
//
#include <hip/hip_runtime.h>

#define DINc 64
#define DHc  128
#define DEc  16
#define Gc   256
#define Rrep 64

typedef unsigned short u16;
typedef unsigned int   u32;
typedef __attribute__((ext_vector_type(8))) short bf8;
typedef __attribute__((ext_vector_type(4))) short bf4;
typedef __attribute__((ext_vector_type(4))) float f4;

__device__ __forceinline__ u16 f2b(float f) {
  u32 u = __builtin_bit_cast(u32, f);
  u32 r = u + 0x7FFFu + ((u >> 16) & 1u);   // round-to-nearest-even
  return (u16)(r >> 16);
}
__device__ __forceinline__ float b2f(u16 h) {
  u32 u = ((u32)h) << 16;
  return __builtin_bit_cast(float, u);
}

// ---------------- convert x fp32 -> bf16 ----------------
__global__ __launch_bounds__(256) void k_cvt(const float* __restrict__ x,
                                             u16* __restrict__ xb, const int n8) {
  for (int i = blockIdx.x * 256 + threadIdx.x; i < n8; i += gridDim.x * 256) {
    float4 f0 = *(const float4*)(x + (size_t)i * 8);
    float4 f1 = *(const float4*)(x + (size_t)i * 8 + 4);
    bf8 v;
    v[0]=(short)f2b(f0.x); v[1]=(short)f2b(f0.y); v[2]=(short)f2b(f0.z); v[3]=(short)f2b(f0.w);
    v[4]=(short)f2b(f1.x); v[5]=(short)f2b(f1.y); v[6]=(short)f2b(f1.z); v[7]=(short)f2b(f1.w);
    *(bf8*)(xb + (size_t)i * 8) = v;
  }
}

// ---------------- CSR build ----------------
__global__ __launch_bounds__(256) void k_hist(const int* __restrict__ dstA, const int nE,
                                              int* __restrict__ deg) {
  for (int i = blockIdx.x * 256 + threadIdx.x; i < nE; i += gridDim.x * 256)
    atomicAdd(&deg[dstA[i]], 1);
}

__global__ __launch_bounds__(1024) void k_scan(const int* __restrict__ deg,
                                               int* __restrict__ rowptr, const int nN) {
  __shared__ int part[1024];
  const int t = threadIdx.x;
  const int C = (nN + 1023) >> 10;
  const int b = min(t * C, nN), e = min(b + C, nN);
  int s = 0;
  for (int i = b; i < e; ++i) s += deg[i];
  part[t] = s;
  __syncthreads();
  for (int off = 1; off < 1024; off <<= 1) {
    int u = (t >= off) ? part[t - off] : 0;
    __syncthreads();
    part[t] += u;
    __syncthreads();
  }
  int run = part[t] - s;
  const int total = part[1023];
  for (int i = b; i < e; ++i) { rowptr[i] = run; run += deg[i]; }
  if (t == 1023) rowptr[nN] = total;
}

__global__ __launch_bounds__(256) void k_fill(const int* __restrict__ dstA,
                                              const int* __restrict__ srcA, const int nE,
                                              const int* __restrict__ rowptr,
                                              int* __restrict__ cursor, int2* __restrict__ csr) {
  for (int i = blockIdx.x * 256 + threadIdx.x; i < nE; i += gridDim.x * 256) {
    const int d = dstA[i];
    const int pos = atomicAdd(&cursor[d], 1);
    csr[rowptr[d] + pos] = make_int2(i, srcA[i]);
  }
}

__global__ __launch_bounds__(256) void k_cnt(const int* __restrict__ batch,
                                             float* __restrict__ cnts, const int nN) {
  for (int i = blockIdx.x * 256 + threadIdx.x; i < nN; i += gridDim.x * 256)
    atomicAdd(&cnts[batch[i]], 1.f);
}

// ---------------- gather aggregation (bf16 node rows) ----------------
template<int D>
__global__ __launch_bounds__(256) void gather_conv(
    const u16* __restrict__ xin, const int2* __restrict__ csr,
    const float* __restrict__ ea, const float* __restrict__ ew,
    const float* __restrict__ eb, const int* __restrict__ rowptr,
    float* __restrict__ aggr, const int nN)
{
  constexpr int PL = D / 64;
  const int lane = threadIdx.x & 63;
  const int wv   = threadIdx.x >> 6;
  float wreg[16 * PL];
  float ebr[PL];
  #pragma unroll
  for (int p = 0; p < PL; ++p) {
    const int d = lane * PL + p;
    ebr[p] = eb[d];
    #pragma unroll
    for (int k = 0; k < 16; ++k) wreg[k * PL + p] = ew[d * 16 + k];
  }
  const float4* __restrict__ ea4 = (const float4*)ea;
  const int gw = blockIdx.x * 4 + wv;
  const int nw = gridDim.x * 4;
  for (int n = gw; n < nN; n += nw) {
    const int beg = rowptr[n], end = rowptr[n + 1];
    float acc[PL];
    #pragma unroll
    for (int p = 0; p < PL; ++p) acc[p] = 0.f;
    for (int chunk = beg; chunk < end; chunk += 64) {
      const int cnt = min(64, end - chunk);
      int2 es = (lane < cnt) ? csr[chunk + lane] : make_int2(0, 0);
      for (int i = 0; i < cnt; ++i) {
        const int e = __shfl(es.x, i);
        const int s = __shfl(es.y, i);
        float eav[16];
        *(float4*)(eav + 0)  = ea4[e * 4 + 0];
        *(float4*)(eav + 4)  = ea4[e * 4 + 1];
        *(float4*)(eav + 8)  = ea4[e * 4 + 2];
        *(float4*)(eav + 12) = ea4[e * 4 + 3];
        if (PL == 1) {
          const float xf = b2f(xin[(size_t)s * 64 + lane]);
          float v = ebr[0];
          #pragma unroll
          for (int k = 0; k < 16; ++k) v = fmaf(eav[k], wreg[k], v);
          acc[0] += fmaxf(xf + v, 0.f);
        } else {
          const u32 uv = *(const u32*)(xin + (size_t)s * 128 + lane * 2);
          const float x0 = b2f((u16)(uv & 0xFFFFu));
          const float x1 = b2f((u16)(uv >> 16));
          float v0 = ebr[0], v1 = ebr[1];
          #pragma unroll
          for (int k = 0; k < 16; ++k) {
            v0 = fmaf(eav[k], wreg[k * 2 + 0], v0);
            v1 = fmaf(eav[k], wreg[k * 2 + 1], v1);
          }
          acc[0] += fmaxf(x0 + v0, 0.f);
          acc[1] += fmaxf(x1 + v1, 0.f);
        }
      }
    }
    if (PL == 1) aggr[(size_t)n * 64 + lane] = acc[0];
    else *(float2*)(aggr + (size_t)n * 128 + lane * 2) = make_float2(acc[0], acc[1]);
  }
}

// ---------------- MFMA node MLP ----------------
// 8 waves x 16 nodes; A = weights [j][k], B = node rows [node][k] (both bf16, LDS XOR-swizzled)
// D layout (verified): node = lane&15, j = jt*16 + (lane>>4)*4 + reg
template<int IN, bool FINAL>
__global__ __launch_bounds__(512) void mlp_mfma(
    const u16* __restrict__ xin, const float* __restrict__ aggr,
    const float* __restrict__ wa, const float* __restrict__ ba,
    const float* __restrict__ wb, const float* __restrict__ bb,
    u16* __restrict__ hout, const int* __restrict__ batch,
    float* __restrict__ sums, const int nN)
{
  __shared__ u16 wa_s[DHc * IN];
  __shared__ u16 wb_s[DHc * DHc];
  __shared__ u16 xa_s[128 * IN];
  __shared__ u16 t_s[128 * DHc];
  const int tid = threadIdx.x;
  constexpr int INC = IN / 8;
  // stage weights bf16, swizzled (dest-indexed, conflict-light)
  for (int c = tid; c < DHc * INC; c += 512) {
    const int row = c / INC, kc = (c % INC) * 8;
    const float* wp = wa + row * IN + kc;
    bf8 v;
    #pragma unroll
    for (int q = 0; q < 8; ++q) v[q] = (short)f2b(wp[q]);
    *(bf8*)(wa_s + ((row * IN + kc) ^ ((row & 7) << 3))) = v;
  }
  for (int c = tid; c < DHc * 16; c += 512) {
    const int row = c >> 4, kc = (c & 15) * 8;
    const float* wp = wb + row * DHc + kc;
    bf8 v;
    #pragma unroll
    for (int q = 0; q < 8; ++q) v[q] = (short)f2b(wp[q]);
    *(bf8*)(wb_s + ((row * DHc + kc) ^ ((row & 7) << 3))) = v;
  }
  const int lane = tid & 63, wv = tid >> 6;
  const int lr = lane & 15, l4 = lane >> 4;
  const int node0 = blockIdx.x * 128 + wv * 16;
  u16* xa_w = xa_s + wv * 16 * IN;    // wave-private
  u16* t_w  = t_s  + wv * 16 * DHc;   // wave-private
  // stage xa = bf16(x + aggr), wave-private rows
  for (int c = lane; c < 16 * INC; c += 64) {
    const int row = c / INC, kc = (c % INC) * 8;
    const int n = min(node0 + row, nN - 1);
    bf8 xv = *(const bf8*)(xin + (size_t)n * IN + kc);
    float4 a0 = *(const float4*)(aggr + (size_t)n * IN + kc);
    float4 a1 = *(const float4*)(aggr + (size_t)n * IN + kc + 4);
    bf8 v;
    v[0] = (short)f2b(b2f((u16)xv[0]) + a0.x);
    v[1] = (short)f2b(b2f((u16)xv[1]) + a0.y);
    v[2] = (short)f2b(b2f((u16)xv[2]) + a0.z);
    v[3] = (short)f2b(b2f((u16)xv[3]) + a0.w);
    v[4] = (short)f2b(b2f((u16)xv[4]) + a1.x);
    v[5] = (short)f2b(b2f((u16)xv[5]) + a1.y);
    v[6] = (short)f2b(b2f((u16)xv[6]) + a1.z);
    v[7] = (short)f2b(b2f((u16)xv[7]) + a1.w);
    *(bf8*)(xa_w + ((row * IN + kc) ^ ((row & 7) << 3))) = v;
  }
  __syncthreads();
  // ---- layer 1: t = relu(xa @ waT + ba) ----
  bf8 bfr[IN / 32];
  #pragma unroll
  for (int ks = 0; ks < IN / 32; ++ks)
    bfr[ks] = *(const bf8*)(xa_w + ((lr * IN + ks * 32 + l4 * 8) ^ ((lr & 7) << 3)));
  #pragma unroll
  for (int jt = 0; jt < 8; ++jt) {
    f4 c = {0.f, 0.f, 0.f, 0.f};
    #pragma unroll
    for (int ks = 0; ks < IN / 32; ++ks) {
      bf8 a = *(const bf8*)(wa_s + (((jt * 16 + lr) * IN + ks * 32 + l4 * 8) ^ ((lr & 7) << 3)));
      c = __builtin_amdgcn_mfma_f32_16x16x32_bf16(a, bfr[ks], c, 0, 0, 0);
    }
    float4 bav = *(const float4*)(ba + jt * 16 + l4 * 4);
    bf4 tv;
    tv[0] = (short)f2b(fmaxf(c[0] + bav.x, 0.f));
    tv[1] = (short)f2b(fmaxf(c[1] + bav.y, 0.f));
    tv[2] = (short)f2b(fmaxf(c[2] + bav.z, 0.f));
    tv[3] = (short)f2b(fmaxf(c[3] + bav.w, 0.f));
    *(bf4*)(t_w + ((lr * DHc + jt * 16 + l4 * 4) ^ ((lr & 7) << 3))) = tv;
  }
  // ---- layer 2: out = relu(t @ wbT + bb) ----
  bf8 tb[4];
  #pragma unroll
  for (int ks = 0; ks < 4; ++ks)
    tb[ks] = *(const bf8*)(t_w + ((lr * DHc + ks * 32 + l4 * 8) ^ ((lr & 7) << 3)));
  const int node = node0 + lr;
  const bool valid = node < nN;
  int gl = 0, g0 = 0, rep = 0; bool uni = false;
  if (FINAL) {
    gl = batch[valid ? node : (nN - 1)];
    g0 = __shfl(gl, 0);
    uni = __all(gl == g0) && (node0 + 16 <= nN);
    rep = (blockIdx.x * 8 + wv) & (Rrep - 1);
  }
  #pragma unroll
  for (int jt = 0; jt < 8; ++jt) {
    f4 c = {0.f, 0.f, 0.f, 0.f};
    #pragma unroll
    for (int ks = 0; ks < 4; ++ks) {
      bf8 a = *(const bf8*)(wb_s + (((jt * 16 + lr) * DHc + ks * 32 + l4 * 8) ^ ((lr & 7) << 3)));
      c = __builtin_amdgcn_mfma_f32_16x16x32_bf16(a, tb[ks], c, 0, 0, 0);
    }
    float4 bbv = *(const float4*)(bb + jt * 16 + l4 * 4);
    float o0 = fmaxf(c[0] + bbv.x, 0.f);
    float o1 = fmaxf(c[1] + bbv.y, 0.f);
    float o2 = fmaxf(c[2] + bbv.z, 0.f);
    float o3 = fmaxf(c[3] + bbv.w, 0.f);
    if (!FINAL) {
      if (valid) {
        bf4 hv;
        hv[0] = (short)f2b(o0); hv[1] = (short)f2b(o1);
        hv[2] = (short)f2b(o2); hv[3] = (short)f2b(o3);
        *(bf4*)(hout + (size_t)node * DHc + jt * 16 + l4 * 4) = hv;
      }
    } else {
      if (uni) {
        #pragma unroll
        for (int off = 1; off < 16; off <<= 1) {
          o0 += __shfl_xor(o0, off);
          o1 += __shfl_xor(o1, off);
          o2 += __shfl_xor(o2, off);
          o3 += __shfl_xor(o3, off);
        }
        if (lr == 0) {
          float* dp = sums + ((size_t)rep * Gc + g0) * DHc + jt * 16 + l4 * 4;
          atomicAdd(dp + 0, o0); atomicAdd(dp + 1, o1);
          atomicAdd(dp + 2, o2); atomicAdd(dp + 3, o3);
        }
      } else if (valid) {
        float* dp = sums + ((size_t)rep * Gc + gl) * DHc + jt * 16 + l4 * 4;
        atomicAdd(dp + 0, o0); atomicAdd(dp + 1, o1);
        atomicAdd(dp + 2, o2); atomicAdd(dp + 3, o3);
      }
    }
  }
}

// ---------------- final: reduce replicas, mean, dot with wf ----------------
__global__ __launch_bounds__(128) void pool_final(
    const float* __restrict__ sums, const float* __restrict__ cnts,
    const float* __restrict__ wf, const float* __restrict__ bf,
    float* __restrict__ out)
{
  const int g = blockIdx.x;
  const int j = threadIdx.x;
  float s = 0.f;
  for (int r = 0; r < Rrep; ++r) s += sums[((size_t)r * Gc + g) * DHc + j];
  const float ct = fmaxf(cnts[g], 1.f);
  __shared__ float red[128];
  red[j] = (s / ct) * wf[j];
  __syncthreads();
  for (int off = 64; off > 0; off >>= 1) { if (j < off) red[j] += red[j + off]; __syncthreads(); }
  if (j == 0) out[g] = red[0] + bf[0];
}

extern "C" void kernel_launch(void* const* d_in, const int* in_sizes, int n_in,
                              void* d_out, int out_size, void* d_ws, size_t ws_size,
                              hipStream_t stream) {
  const float* x    = (const float*)d_in[0];
  const int*   ei   = (const int*)d_in[1];
  const float* ea   = (const float*)d_in[2];
  const int*   batch= (const int*)d_in[3];
  const float* ew1  = (const float*)d_in[4];
  const float* eb1  = (const float*)d_in[5];
  const float* w1a  = (const float*)d_in[6];
  const float* b1a  = (const float*)d_in[7];
  const float* w1b  = (const float*)d_in[8];
  const float* b1b  = (const float*)d_in[9];
  const float* ew2  = (const float*)d_in[10];
  const float* eb2  = (const float*)d_in[11];
  const float* w2a  = (const float*)d_in[12];
  const float* b2a  = (const float*)d_in[13];
  const float* w2b  = (const float*)d_in[14];
  const float* b2b  = (const float*)d_in[15];
  const float* wf   = (const float*)d_in[16];
  const float* bf   = (const float*)d_in[17];
  float* out = (float*)d_out;

  const int nN = in_sizes[0] / DINc;
  const int nE = in_sizes[1] / 2;
  const int* srcA = ei;
  const int* dstA = ei + nE;

  char* wsb = (char*)d_ws;
  size_t o = 0;
  u16*   h1b    = (u16*)  (wsb + o); o += (size_t)nN * DHc * 2;
  u16*   xb     = (u16*)  (wsb + o); o += (size_t)nN * DINc * 2;
  float* aggr   = (float*)(wsb + o); o += (size_t)nN * DHc * 4;
  float* sums   = (float*)(wsb + o); o += (size_t)Rrep * Gc * DHc * 4;
  float* cnts   = (float*)(wsb + o); o += (size_t)Gc * 4;
  int*   deg    = (int*)  (wsb + o); o += (size_t)nN * 4;
  int*   cursor = (int*)  (wsb + o); o += (size_t)nN * 4;
  int*   rowptr = (int*)  (wsb + o); o += (size_t)(nN + 1) * 4; o = (o + 15) & ~(size_t)15;
  int2*  csr    = (int2*) (wsb + o); o += (size_t)nE * 8;
  (void)ws_size; (void)n_in; (void)out_size;

  hipMemsetAsync(sums, 0, (size_t)Rrep * Gc * DHc * 4 + (size_t)Gc * 4, stream);
  hipMemsetAsync(deg, 0, (size_t)nN * 8, stream);

  k_cvt<<<1024, 256, 0, stream>>>(x, xb, nN * DINc / 8);
  k_hist<<<1024, 256, 0, stream>>>(dstA, nE, deg);
  k_scan<<<1, 1024, 0, stream>>>(deg, rowptr, nN);
  k_fill<<<1024, 256, 0, stream>>>(dstA, srcA, nE, rowptr, cursor, csr);
  k_cnt<<<256, 256, 0, stream>>>(batch, cnts, nN);

  const int nt = (nN + 127) / 128;
  gather_conv<DINc><<<2048, 256, 0, stream>>>(xb, csr, ea, ew1, eb1, rowptr, aggr, nN);
  mlp_mfma<DINc, false><<<nt, 512, 0, stream>>>(xb, aggr, w1a, b1a, w1b, b1b,
                                                h1b, nullptr, nullptr, nN);
  gather_conv<DHc><<<2048, 256, 0, stream>>>(h1b, csr, ea, ew2, eb2, rowptr, aggr, nN);
  mlp_mfma<DHc, true><<<nt, 512, 0, stream>>>(h1b, aggr, w2a, b2a, w2b, b2b,
                                              nullptr, batch, sums, nN);
  pool_final<<<Gc, 128, 0, stream>>>(sums, cnts, wf, bf, out);
}

// Round 4
// 868.679 us; speedup vs baseline: 1.9427x; 1.3184x over previous
//
#include <hip/hip_runtime.h>

#define DINc 64
#define DHc  128
#define DEc  16
#define Gc   256
#define Rrep 64
#define SCB  1024

typedef unsigned short u16;
typedef unsigned int   u32;
typedef __attribute__((ext_vector_type(8))) short bf8;
typedef __attribute__((ext_vector_type(4))) short bf4;
typedef __attribute__((ext_vector_type(4))) float f4;

__device__ __forceinline__ u16 f2b(float f) {
  u32 u = __builtin_bit_cast(u32, f);
  u32 r = u + 0x7FFFu + ((u >> 16) & 1u);   // round-to-nearest-even
  return (u16)(r >> 16);
}
__device__ __forceinline__ float b2f(u16 h) {
  u32 u = ((u32)h) << 16;
  return __builtin_bit_cast(float, u);
}

// ---------------- convert x fp32 -> bf16 ----------------
__global__ __launch_bounds__(256) void k_cvt(const float* __restrict__ x,
                                             u16* __restrict__ xb, const int n8) {
  for (int i = blockIdx.x * 256 + threadIdx.x; i < n8; i += gridDim.x * 256) {
    float4 f0 = *(const float4*)(x + (size_t)i * 8);
    float4 f1 = *(const float4*)(x + (size_t)i * 8 + 4);
    bf8 v;
    v[0]=(short)f2b(f0.x); v[1]=(short)f2b(f0.y); v[2]=(short)f2b(f0.z); v[3]=(short)f2b(f0.w);
    v[4]=(short)f2b(f1.x); v[5]=(short)f2b(f1.y); v[6]=(short)f2b(f1.z); v[7]=(short)f2b(f1.w);
    *(bf8*)(xb + (size_t)i * 8) = v;
  }
}

// ---------------- CSR build ----------------
__global__ __launch_bounds__(256) void k_hist(const int* __restrict__ dstA, const int nE,
                                              int* __restrict__ deg) {
  for (int i = blockIdx.x * 256 + threadIdx.x; i < nE; i += gridDim.x * 256)
    atomicAdd(&deg[dstA[i]], 1);
}

__global__ __launch_bounds__(256) void k_scan_blk(const int* __restrict__ deg,
                                                  int* __restrict__ bsum, const int nN) {
  const int b = blockIdx.x, t = threadIdx.x;
  const int i0 = b * SCB + t * 4;
  int s = 0;
  #pragma unroll
  for (int q = 0; q < 4; ++q) { const int i = i0 + q; if (i < nN) s += deg[i]; }
  #pragma unroll
  for (int off = 32; off > 0; off >>= 1) s += __shfl_down(s, off);
  __shared__ int ws[4];
  if ((t & 63) == 0) ws[t >> 6] = s;
  __syncthreads();
  if (t == 0) bsum[b] = ws[0] + ws[1] + ws[2] + ws[3];
}

__global__ __launch_bounds__(256) void k_scan_fin(const int* __restrict__ deg,
                                                  const int* __restrict__ bsum,
                                                  int* __restrict__ rowptr,
                                                  const int nN, const int nB) {
  const int b = blockIdx.x, t = threadIdx.x;
  int p = 0;
  for (int i = t; i < b; i += 256) p += bsum[i];
  #pragma unroll
  for (int off = 32; off > 0; off >>= 1) p += __shfl_down(p, off);
  __shared__ int ws[4];
  __shared__ int sc[256];
  if ((t & 63) == 0) ws[t >> 6] = p;
  const int i0 = b * SCB + t * 4;
  int vals[4]; int s = 0;
  #pragma unroll
  for (int q = 0; q < 4; ++q) { const int i = i0 + q; vals[q] = (i < nN) ? deg[i] : 0; s += vals[q]; }
  sc[t] = s;
  __syncthreads();
  const int boff = ws[0] + ws[1] + ws[2] + ws[3];
  for (int off = 1; off < 256; off <<= 1) {
    int u = (t >= off) ? sc[t - off] : 0;
    __syncthreads();
    sc[t] += u;
    __syncthreads();
  }
  int run = boff + sc[t] - s;
  #pragma unroll
  for (int q = 0; q < 4; ++q) { const int i = i0 + q; if (i < nN) rowptr[i] = run; run += vals[q]; }
  if (b == nB - 1 && t == 255) rowptr[nN] = run;
}

__global__ __launch_bounds__(256) void k_fill(const int* __restrict__ dstA,
                                              const int* __restrict__ srcA, const int nE,
                                              const int* __restrict__ rowptr,
                                              int* __restrict__ cursor, int2* __restrict__ csr) {
  for (int i = blockIdx.x * 256 + threadIdx.x; i < nE; i += gridDim.x * 256) {
    const int d = dstA[i];
    const int pos = atomicAdd(&cursor[d], 1);
    csr[rowptr[d] + pos] = make_int2(i, srcA[i]);
  }
}

__global__ __launch_bounds__(256) void k_cnt(const int* __restrict__ batch,
                                             float* __restrict__ cnts, const int nN) {
  for (int i = blockIdx.x * 256 + threadIdx.x; i < nN; i += gridDim.x * 256)
    atomicAdd(&cnts[batch[i]], 1.f);
}

// ---------------- gather aggregation (bf16 node rows, scalar-uniform edge loads) ----------------
template<int D>
__global__ __launch_bounds__(256) void gather_conv(
    const u16* __restrict__ xin, const int2* __restrict__ csr,
    const float* __restrict__ ea, const float* __restrict__ ew,
    const float* __restrict__ eb, const int* __restrict__ rowptr,
    float* __restrict__ aggr, const int nN)
{
  constexpr int PL = D / 64;
  const int lane = threadIdx.x & 63;
  const int wv   = threadIdx.x >> 6;
  float wreg[16 * PL];
  float ebr[PL];
  #pragma unroll
  for (int p = 0; p < PL; ++p) {
    const int d = lane * PL + p;
    ebr[p] = eb[d];
    #pragma unroll
    for (int k = 0; k < 16; ++k) wreg[k * PL + p] = ew[d * 16 + k];
  }
  const int gw = blockIdx.x * 4 + wv;
  const int nw = gridDim.x * 4;
  for (int n = gw; n < nN; n += nw) {
    const int beg = rowptr[n], end = rowptr[n + 1];
    float acc[PL];
    #pragma unroll
    for (int p = 0; p < PL; ++p) acc[p] = 0.f;
    for (int chunk = beg; chunk < end; chunk += 64) {
      const int cnt = min(64, end - chunk);
      int2 es = (lane < cnt) ? csr[chunk + lane] : make_int2(0, 0);
      #pragma unroll 4
      for (int i = 0; i < cnt; ++i) {
        const int e = __builtin_amdgcn_readlane(es.x, i);  // wave-uniform scalar
        const int s = __builtin_amdgcn_readlane(es.y, i);  // -> s_load / saddr forms
        const float* __restrict__ eap = ea + (size_t)e * 16;
        if (PL == 1) {
          float v = ebr[0];
          #pragma unroll
          for (int k = 0; k < 16; ++k) v = fmaf(eap[k], wreg[k], v);
          const float xf = b2f(xin[(size_t)s * 64 + lane]);
          acc[0] += fmaxf(xf + v, 0.f);
        } else {
          float v0 = ebr[0], v1 = ebr[1];
          #pragma unroll
          for (int k = 0; k < 16; ++k) {
            const float eav = eap[k];
            v0 = fmaf(eav, wreg[k * 2 + 0], v0);
            v1 = fmaf(eav, wreg[k * 2 + 1], v1);
          }
          const u32 uv = *(const u32*)(xin + (size_t)s * 128 + lane * 2);
          acc[0] += fmaxf(b2f((u16)(uv & 0xFFFFu)) + v0, 0.f);
          acc[1] += fmaxf(b2f((u16)(uv >> 16)) + v1, 0.f);
        }
      }
    }
    if (PL == 1) aggr[(size_t)n * 64 + lane] = acc[0];
    else *(float2*)(aggr + (size_t)n * 128 + lane * 2) = make_float2(acc[0], acc[1]);
  }
}

// ---------------- MFMA node MLP (persistent blocks, weights staged once) ----------------
template<int IN, bool FINAL>
__global__ __launch_bounds__(512) void mlp_mfma(
    const u16* __restrict__ xin, const float* __restrict__ aggr,
    const float* __restrict__ wa, const float* __restrict__ ba,
    const float* __restrict__ wb, const float* __restrict__ bb,
    u16* __restrict__ hout, const int* __restrict__ batch,
    float* __restrict__ sums, const int nN, const int nTiles)
{
  __shared__ u16 wa_s[DHc * IN];
  __shared__ u16 wb_s[DHc * DHc];
  __shared__ u16 xa_s[128 * IN];
  __shared__ u16 t_s[128 * DHc];
  const int tid = threadIdx.x;
  constexpr int INC = IN / 8;
  for (int c = tid; c < DHc * INC; c += 512) {
    const int row = c / INC, kc = (c % INC) * 8;
    const float* wp = wa + row * IN + kc;
    bf8 v;
    #pragma unroll
    for (int q = 0; q < 8; ++q) v[q] = (short)f2b(wp[q]);
    *(bf8*)(wa_s + ((row * IN + kc) ^ ((row & 7) << 3))) = v;
  }
  for (int c = tid; c < DHc * 16; c += 512) {
    const int row = c >> 4, kc = (c & 15) * 8;
    const float* wp = wb + row * DHc + kc;
    bf8 v;
    #pragma unroll
    for (int q = 0; q < 8; ++q) v[q] = (short)f2b(wp[q]);
    *(bf8*)(wb_s + ((row * DHc + kc) ^ ((row & 7) << 3))) = v;
  }
  const int lane = tid & 63, wv = tid >> 6;
  const int lr = lane & 15, l4 = lane >> 4;
  u16* xa_w = xa_s + wv * 16 * IN;    // wave-private
  u16* t_w  = t_s  + wv * 16 * DHc;   // wave-private
  __syncthreads();
  for (int tile = blockIdx.x; tile < nTiles; tile += gridDim.x) {
    const int node0 = tile * 128 + wv * 16;
    // stage xa = bf16(x + aggr), wave-private rows
    for (int c = lane; c < 16 * INC; c += 64) {
      const int row = c / INC, kc = (c % INC) * 8;
      const int n = min(node0 + row, nN - 1);
      bf8 xv = *(const bf8*)(xin + (size_t)n * IN + kc);
      float4 a0 = *(const float4*)(aggr + (size_t)n * IN + kc);
      float4 a1 = *(const float4*)(aggr + (size_t)n * IN + kc + 4);
      bf8 v;
      v[0] = (short)f2b(b2f((u16)xv[0]) + a0.x);
      v[1] = (short)f2b(b2f((u16)xv[1]) + a0.y);
      v[2] = (short)f2b(b2f((u16)xv[2]) + a0.z);
      v[3] = (short)f2b(b2f((u16)xv[3]) + a0.w);
      v[4] = (short)f2b(b2f((u16)xv[4]) + a1.x);
      v[5] = (short)f2b(b2f((u16)xv[5]) + a1.y);
      v[6] = (short)f2b(b2f((u16)xv[6]) + a1.z);
      v[7] = (short)f2b(b2f((u16)xv[7]) + a1.w);
      *(bf8*)(xa_w + ((row * IN + kc) ^ ((row & 7) << 3))) = v;
    }
    // ---- layer 1: t = relu(xa @ waT + ba) ----
    bf8 bfr[IN / 32];
    #pragma unroll
    for (int ks = 0; ks < IN / 32; ++ks)
      bfr[ks] = *(const bf8*)(xa_w + ((lr * IN + ks * 32 + l4 * 8) ^ ((lr & 7) << 3)));
    #pragma unroll
    for (int jt = 0; jt < 8; ++jt) {
      f4 c = {0.f, 0.f, 0.f, 0.f};
      #pragma unroll
      for (int ks = 0; ks < IN / 32; ++ks) {
        bf8 a = *(const bf8*)(wa_s + (((jt * 16 + lr) * IN + ks * 32 + l4 * 8) ^ ((lr & 7) << 3)));
        c = __builtin_amdgcn_mfma_f32_16x16x32_bf16(a, bfr[ks], c, 0, 0, 0);
      }
      float4 bav = *(const float4*)(ba + jt * 16 + l4 * 4);
      bf4 tv;
      tv[0] = (short)f2b(fmaxf(c[0] + bav.x, 0.f));
      tv[1] = (short)f2b(fmaxf(c[1] + bav.y, 0.f));
      tv[2] = (short)f2b(fmaxf(c[2] + bav.z, 0.f));
      tv[3] = (short)f2b(fmaxf(c[3] + bav.w, 0.f));
      *(bf4*)(t_w + ((lr * DHc + jt * 16 + l4 * 4) ^ ((lr & 7) << 3))) = tv;
    }
    // ---- layer 2: out = relu(t @ wbT + bb) ----
    bf8 tb[4];
    #pragma unroll
    for (int ks = 0; ks < 4; ++ks)
      tb[ks] = *(const bf8*)(t_w + ((lr * DHc + ks * 32 + l4 * 8) ^ ((lr & 7) << 3)));
    const int node = node0 + lr;
    const bool valid = node < nN;
    int gl = 0, g0 = 0, rep = 0; bool uni = false;
    if (FINAL) {
      gl = batch[valid ? node : (nN - 1)];
      g0 = __shfl(gl, 0);
      uni = __all(gl == g0) && (node0 + 16 <= nN);
      rep = (tile * 8 + wv) & (Rrep - 1);
    }
    #pragma unroll
    for (int jt = 0; jt < 8; ++jt) {
      f4 c = {0.f, 0.f, 0.f, 0.f};
      #pragma unroll
      for (int ks = 0; ks < 4; ++ks) {
        bf8 a = *(const bf8*)(wb_s + (((jt * 16 + lr) * DHc + ks * 32 + l4 * 8) ^ ((lr & 7) << 3)));
        c = __builtin_amdgcn_mfma_f32_16x16x32_bf16(a, tb[ks], c, 0, 0, 0);
      }
      float4 bbv = *(const float4*)(bb + jt * 16 + l4 * 4);
      float o0 = fmaxf(c[0] + bbv.x, 0.f);
      float o1 = fmaxf(c[1] + bbv.y, 0.f);
      float o2 = fmaxf(c[2] + bbv.z, 0.f);
      float o3 = fmaxf(c[3] + bbv.w, 0.f);
      if (!FINAL) {
        if (valid) {
          bf4 hv;
          hv[0] = (short)f2b(o0); hv[1] = (short)f2b(o1);
          hv[2] = (short)f2b(o2); hv[3] = (short)f2b(o3);
          *(bf4*)(hout + (size_t)node * DHc + jt * 16 + l4 * 4) = hv;
        }
      } else {
        if (uni) {
          #pragma unroll
          for (int off = 1; off < 16; off <<= 1) {
            o0 += __shfl_xor(o0, off);
            o1 += __shfl_xor(o1, off);
            o2 += __shfl_xor(o2, off);
            o3 += __shfl_xor(o3, off);
          }
          if (lr == 0) {
            float* dp = sums + ((size_t)rep * Gc + g0) * DHc + jt * 16 + l4 * 4;
            atomicAdd(dp + 0, o0); atomicAdd(dp + 1, o1);
            atomicAdd(dp + 2, o2); atomicAdd(dp + 3, o3);
          }
        } else if (valid) {
          float* dp = sums + ((size_t)rep * Gc + gl) * DHc + jt * 16 + l4 * 4;
          atomicAdd(dp + 0, o0); atomicAdd(dp + 1, o1);
          atomicAdd(dp + 2, o2); atomicAdd(dp + 3, o3);
        }
      }
    }
  }
}

// ---------------- final: reduce replicas, mean, dot with wf ----------------
__global__ __launch_bounds__(128) void pool_final(
    const float* __restrict__ sums, const float* __restrict__ cnts,
    const float* __restrict__ wf, const float* __restrict__ bf,
    float* __restrict__ out)
{
  const int g = blockIdx.x;
  const int j = threadIdx.x;
  float s = 0.f;
  for (int r = 0; r < Rrep; ++r) s += sums[((size_t)r * Gc + g) * DHc + j];
  const float ct = fmaxf(cnts[g], 1.f);
  __shared__ float red[128];
  red[j] = (s / ct) * wf[j];
  __syncthreads();
  for (int off = 64; off > 0; off >>= 1) { if (j < off) red[j] += red[j + off]; __syncthreads(); }
  if (j == 0) out[g] = red[0] + bf[0];
}

extern "C" void kernel_launch(void* const* d_in, const int* in_sizes, int n_in,
                              void* d_out, int out_size, void* d_ws, size_t ws_size,
                              hipStream_t stream) {
  const float* x    = (const float*)d_in[0];
  const int*   ei   = (const int*)d_in[1];
  const float* ea   = (const float*)d_in[2];
  const int*   batch= (const int*)d_in[3];
  const float* ew1  = (const float*)d_in[4];
  const float* eb1  = (const float*)d_in[5];
  const float* w1a  = (const float*)d_in[6];
  const float* b1a  = (const float*)d_in[7];
  const float* w1b  = (const float*)d_in[8];
  const float* b1b  = (const float*)d_in[9];
  const float* ew2  = (const float*)d_in[10];
  const float* eb2  = (const float*)d_in[11];
  const float* w2a  = (const float*)d_in[12];
  const float* b2a  = (const float*)d_in[13];
  const float* w2b  = (const float*)d_in[14];
  const float* b2b  = (const float*)d_in[15];
  const float* wf   = (const float*)d_in[16];
  const float* bf   = (const float*)d_in[17];
  float* out = (float*)d_out;

  const int nN = in_sizes[0] / DINc;
  const int nE = in_sizes[1] / 2;
  const int* srcA = ei;
  const int* dstA = ei + nE;

  char* wsb = (char*)d_ws;
  size_t o = 0;
  u16*   h1b    = (u16*)  (wsb + o); o += (size_t)nN * DHc * 2;
  u16*   xb     = (u16*)  (wsb + o); o += (size_t)nN * DINc * 2;
  float* aggr   = (float*)(wsb + o); o += (size_t)nN * DHc * 4;
  float* sums   = (float*)(wsb + o); o += (size_t)Rrep * Gc * DHc * 4;
  float* cnts   = (float*)(wsb + o); o += (size_t)Gc * 4;
  int*   deg    = (int*)  (wsb + o); o += (size_t)nN * 4;
  int*   cursor = (int*)  (wsb + o); o += (size_t)nN * 4;
  int*   rowptr = (int*)  (wsb + o); o += (size_t)(nN + 1) * 4;
  int*   bsum   = (int*)  (wsb + o); o += (size_t)((nN + SCB - 1) / SCB) * 4; o = (o + 15) & ~(size_t)15;
  int2*  csr    = (int2*) (wsb + o); o += (size_t)nE * 8;
  (void)ws_size; (void)n_in; (void)out_size;

  hipMemsetAsync(sums, 0, (size_t)Rrep * Gc * DHc * 4 + (size_t)Gc * 4, stream);
  hipMemsetAsync(deg, 0, (size_t)nN * 8, stream);

  const int nB = (nN + SCB - 1) / SCB;
  k_cvt<<<1024, 256, 0, stream>>>(x, xb, nN * DINc / 8);
  k_hist<<<1024, 256, 0, stream>>>(dstA, nE, deg);
  k_scan_blk<<<nB, 256, 0, stream>>>(deg, bsum, nN);
  k_scan_fin<<<nB, 256, 0, stream>>>(deg, bsum, rowptr, nN, nB);
  k_fill<<<1024, 256, 0, stream>>>(dstA, srcA, nE, rowptr, cursor, csr);
  k_cnt<<<256, 256, 0, stream>>>(batch, cnts, nN);

  const int nt = (nN + 127) / 128;
  gather_conv<DINc><<<2048, 256, 0, stream>>>(xb, csr, ea, ew1, eb1, rowptr, aggr, nN);
  mlp_mfma<DINc, false><<<256, 512, 0, stream>>>(xb, aggr, w1a, b1a, w1b, b1b,
                                                 h1b, nullptr, nullptr, nN, nt);
  gather_conv<DHc><<<2048, 256, 0, stream>>>(h1b, csr, ea, ew2, eb2, rowptr, aggr, nN);
  mlp_mfma<DHc, true><<<256, 512, 0, stream>>>(h1b, aggr, w2a, b2a, w2b, b2b,
                                               nullptr, batch, sums, nN, nt);
  pool_final<<<Gc, 128, 0, stream>>>(sums, cnts, wf, bf, out);
}

// Round 5
// 679.392 us; speedup vs baseline: 2.4840x; 1.2786x over previous
//
#include <hip/hip_runtime.h>

#define DINc 64
#define DHc  128
#define DEc  16
#define Gc   256
#define Rrep 64
#define SCB  1024

typedef unsigned short u16;
typedef unsigned int   u32;
typedef __attribute__((ext_vector_type(8))) short bf8;
typedef __attribute__((ext_vector_type(4))) short bf4;
typedef __attribute__((ext_vector_type(4))) float f4;

__device__ __forceinline__ u16 f2b(float f) {
  u32 u = __builtin_bit_cast(u32, f);
  u32 r = u + 0x7FFFu + ((u >> 16) & 1u);   // round-to-nearest-even
  return (u16)(r >> 16);
}
__device__ __forceinline__ float b2f(u16 h) {
  u32 u = ((u32)h) << 16;
  return __builtin_bit_cast(float, u);
}

// ---------------- convert x fp32 -> bf16 ----------------
__global__ __launch_bounds__(256) void k_cvt(const float* __restrict__ x,
                                             u16* __restrict__ xb, const int n8) {
  for (int i = blockIdx.x * 256 + threadIdx.x; i < n8; i += gridDim.x * 256) {
    float4 f0 = *(const float4*)(x + (size_t)i * 8);
    float4 f1 = *(const float4*)(x + (size_t)i * 8 + 4);
    bf8 v;
    v[0]=(short)f2b(f0.x); v[1]=(short)f2b(f0.y); v[2]=(short)f2b(f0.z); v[3]=(short)f2b(f0.w);
    v[4]=(short)f2b(f1.x); v[5]=(short)f2b(f1.y); v[6]=(short)f2b(f1.z); v[7]=(short)f2b(f1.w);
    *(bf8*)(xb + (size_t)i * 8) = v;
  }
}

// ---------------- CSR build ----------------
__global__ __launch_bounds__(256) void k_hist(const int* __restrict__ dstA, const int nE,
                                              int* __restrict__ deg) {
  for (int i = blockIdx.x * 256 + threadIdx.x; i < nE; i += gridDim.x * 256)
    atomicAdd(&deg[dstA[i]], 1);
}

__global__ __launch_bounds__(256) void k_scan_blk(const int* __restrict__ deg,
                                                  int* __restrict__ bsum, const int nN) {
  const int b = blockIdx.x, t = threadIdx.x;
  const int i0 = b * SCB + t * 4;
  int s = 0;
  #pragma unroll
  for (int q = 0; q < 4; ++q) { const int i = i0 + q; if (i < nN) s += deg[i]; }
  #pragma unroll
  for (int off = 32; off > 0; off >>= 1) s += __shfl_down(s, off);
  __shared__ int ws[4];
  if ((t & 63) == 0) ws[t >> 6] = s;
  __syncthreads();
  if (t == 0) bsum[b] = ws[0] + ws[1] + ws[2] + ws[3];
}

__global__ __launch_bounds__(256) void k_scan_fin(const int* __restrict__ deg,
                                                  const int* __restrict__ bsum,
                                                  int* __restrict__ rowptr,
                                                  const int nN, const int nB) {
  const int b = blockIdx.x, t = threadIdx.x;
  int p = 0;
  for (int i = t; i < b; i += 256) p += bsum[i];
  #pragma unroll
  for (int off = 32; off > 0; off >>= 1) p += __shfl_down(p, off);
  __shared__ int ws[4];
  __shared__ int sc[256];
  if ((t & 63) == 0) ws[t >> 6] = p;
  const int i0 = b * SCB + t * 4;
  int vals[4]; int s = 0;
  #pragma unroll
  for (int q = 0; q < 4; ++q) { const int i = i0 + q; vals[q] = (i < nN) ? deg[i] : 0; s += vals[q]; }
  sc[t] = s;
  __syncthreads();
  const int boff = ws[0] + ws[1] + ws[2] + ws[3];
  for (int off = 1; off < 256; off <<= 1) {
    int u = (t >= off) ? sc[t - off] : 0;
    __syncthreads();
    sc[t] += u;
    __syncthreads();
  }
  int run = boff + sc[t] - s;
  #pragma unroll
  for (int q = 0; q < 4; ++q) { const int i = i0 + q; if (i < nN) rowptr[i] = run; run += vals[q]; }
  if (b == nB - 1 && t == 255) rowptr[nN] = run;
}

__global__ __launch_bounds__(256) void k_fill(const int* __restrict__ dstA,
                                              const int* __restrict__ srcA, const int nE,
                                              const int* __restrict__ rowptr,
                                              int* __restrict__ cursor, int2* __restrict__ csr) {
  for (int i = blockIdx.x * 256 + threadIdx.x; i < nE; i += gridDim.x * 256) {
    const int d = dstA[i];
    const int pos = atomicAdd(&cursor[d], 1);
    csr[rowptr[d] + pos] = make_int2(i, srcA[i]);
  }
}

// batch is sorted: count per graph = segment length via two binary searches. No atomics.
__global__ __launch_bounds__(256) void k_cnt_bs(const int* __restrict__ batch,
                                                float* __restrict__ cnts, const int nN) {
  const int g = threadIdx.x;
  if (g >= Gc) return;
  int lo = 0, hi = nN;
  while (lo < hi) { int m = (lo + hi) >> 1; if (batch[m] < g) lo = m + 1; else hi = m; }
  int lo2 = lo, hi2 = nN;
  while (lo2 < hi2) { int m = (lo2 + hi2) >> 1; if (batch[m] < g + 1) lo2 = m + 1; else hi2 = m; }
  cnts[g] = (float)(lo2 - lo);
}

// ---------------- gather aggregation (bf16 node rows, scalar-uniform edge loads) ----------------
template<int D>
__global__ __launch_bounds__(256) void gather_conv(
    const u16* __restrict__ xin, const int2* __restrict__ csr,
    const float* __restrict__ ea, const float* __restrict__ ew,
    const float* __restrict__ eb, const int* __restrict__ rowptr,
    float* __restrict__ aggr, const int nN)
{
  constexpr int PL = D / 64;
  const int lane = threadIdx.x & 63;
  const int wv   = threadIdx.x >> 6;
  float wreg[16 * PL];
  float ebr[PL];
  #pragma unroll
  for (int p = 0; p < PL; ++p) {
    const int d = lane * PL + p;
    ebr[p] = eb[d];
    #pragma unroll
    for (int k = 0; k < 16; ++k) wreg[k * PL + p] = ew[d * 16 + k];
  }
  const int gw = blockIdx.x * 4 + wv;
  const int nw = gridDim.x * 4;
  for (int n = gw; n < nN; n += nw) {
    const int beg = rowptr[n], end = rowptr[n + 1];
    float acc[PL];
    #pragma unroll
    for (int p = 0; p < PL; ++p) acc[p] = 0.f;
    for (int chunk = beg; chunk < end; chunk += 64) {
      const int cnt = min(64, end - chunk);
      int2 es = (lane < cnt) ? csr[chunk + lane] : make_int2(0, 0);
      #pragma unroll 4
      for (int i = 0; i < cnt; ++i) {
        const int e = __builtin_amdgcn_readlane(es.x, i);  // wave-uniform scalar
        const int s = __builtin_amdgcn_readlane(es.y, i);  // -> s_load / saddr forms
        const float* __restrict__ eap = ea + (size_t)e * 16;
        if (PL == 1) {
          float v = ebr[0];
          #pragma unroll
          for (int k = 0; k < 16; ++k) v = fmaf(eap[k], wreg[k], v);
          const float xf = b2f(xin[(size_t)s * 64 + lane]);
          acc[0] += fmaxf(xf + v, 0.f);
        } else {
          float v0 = ebr[0], v1 = ebr[1];
          #pragma unroll
          for (int k = 0; k < 16; ++k) {
            const float eav = eap[k];
            v0 = fmaf(eav, wreg[k * 2 + 0], v0);
            v1 = fmaf(eav, wreg[k * 2 + 1], v1);
          }
          const u32 uv = *(const u32*)(xin + (size_t)s * 128 + lane * 2);
          acc[0] += fmaxf(b2f((u16)(uv & 0xFFFFu)) + v0, 0.f);
          acc[1] += fmaxf(b2f((u16)(uv >> 16)) + v1, 0.f);
        }
      }
    }
    if (PL == 1) aggr[(size_t)n * 64 + lane] = acc[0];
    else *(float2*)(aggr + (size_t)n * 128 + lane * 2) = make_float2(acc[0], acc[1]);
  }
}

// ---------------- MFMA node MLP (persistent blocks, weights staged once) ----------------
template<int IN, bool FINAL>
__global__ __launch_bounds__(512) void mlp_mfma(
    const u16* __restrict__ xin, const float* __restrict__ aggr,
    const float* __restrict__ wa, const float* __restrict__ ba,
    const float* __restrict__ wb, const float* __restrict__ bb,
    u16* __restrict__ hout, const int* __restrict__ batch,
    float* __restrict__ sums, const int nN, const int nTiles)
{
  __shared__ u16 wa_s[DHc * IN];
  __shared__ u16 wb_s[DHc * DHc];
  __shared__ u16 xa_s[128 * IN];
  __shared__ u16 t_s[128 * DHc];
  const int tid = threadIdx.x;
  constexpr int INC = IN / 8;
  for (int c = tid; c < DHc * INC; c += 512) {
    const int row = c / INC, kc = (c % INC) * 8;
    const float* wp = wa + row * IN + kc;
    bf8 v;
    #pragma unroll
    for (int q = 0; q < 8; ++q) v[q] = (short)f2b(wp[q]);
    *(bf8*)(wa_s + ((row * IN + kc) ^ ((row & 7) << 3))) = v;
  }
  for (int c = tid; c < DHc * 16; c += 512) {
    const int row = c >> 4, kc = (c & 15) * 8;
    const float* wp = wb + row * DHc + kc;
    bf8 v;
    #pragma unroll
    for (int q = 0; q < 8; ++q) v[q] = (short)f2b(wp[q]);
    *(bf8*)(wb_s + ((row * DHc + kc) ^ ((row & 7) << 3))) = v;
  }
  const int lane = tid & 63, wv = tid >> 6;
  const int lr = lane & 15, l4 = lane >> 4;
  u16* xa_w = xa_s + wv * 16 * IN;    // wave-private
  u16* t_w  = t_s  + wv * 16 * DHc;   // wave-private
  __syncthreads();
  for (int tile = blockIdx.x; tile < nTiles; tile += gridDim.x) {
    const int node0 = tile * 128 + wv * 16;
    // stage xa = bf16(x + aggr), wave-private rows
    for (int c = lane; c < 16 * INC; c += 64) {
      const int row = c / INC, kc = (c % INC) * 8;
      const int n = min(node0 + row, nN - 1);
      bf8 xv = *(const bf8*)(xin + (size_t)n * IN + kc);
      float4 a0 = *(const float4*)(aggr + (size_t)n * IN + kc);
      float4 a1 = *(const float4*)(aggr + (size_t)n * IN + kc + 4);
      bf8 v;
      v[0] = (short)f2b(b2f((u16)xv[0]) + a0.x);
      v[1] = (short)f2b(b2f((u16)xv[1]) + a0.y);
      v[2] = (short)f2b(b2f((u16)xv[2]) + a0.z);
      v[3] = (short)f2b(b2f((u16)xv[3]) + a0.w);
      v[4] = (short)f2b(b2f((u16)xv[4]) + a1.x);
      v[5] = (short)f2b(b2f((u16)xv[5]) + a1.y);
      v[6] = (short)f2b(b2f((u16)xv[6]) + a1.z);
      v[7] = (short)f2b(b2f((u16)xv[7]) + a1.w);
      *(bf8*)(xa_w + ((row * IN + kc) ^ ((row & 7) << 3))) = v;
    }
    // ---- layer 1: t = relu(xa @ waT + ba) ----
    bf8 bfr[IN / 32];
    #pragma unroll
    for (int ks = 0; ks < IN / 32; ++ks)
      bfr[ks] = *(const bf8*)(xa_w + ((lr * IN + ks * 32 + l4 * 8) ^ ((lr & 7) << 3)));
    #pragma unroll
    for (int jt = 0; jt < 8; ++jt) {
      f4 c = {0.f, 0.f, 0.f, 0.f};
      #pragma unroll
      for (int ks = 0; ks < IN / 32; ++ks) {
        bf8 a = *(const bf8*)(wa_s + (((jt * 16 + lr) * IN + ks * 32 + l4 * 8) ^ ((lr & 7) << 3)));
        c = __builtin_amdgcn_mfma_f32_16x16x32_bf16(a, bfr[ks], c, 0, 0, 0);
      }
      float4 bav = *(const float4*)(ba + jt * 16 + l4 * 4);
      bf4 tv;
      tv[0] = (short)f2b(fmaxf(c[0] + bav.x, 0.f));
      tv[1] = (short)f2b(fmaxf(c[1] + bav.y, 0.f));
      tv[2] = (short)f2b(fmaxf(c[2] + bav.z, 0.f));
      tv[3] = (short)f2b(fmaxf(c[3] + bav.w, 0.f));
      *(bf4*)(t_w + ((lr * DHc + jt * 16 + l4 * 4) ^ ((lr & 7) << 3))) = tv;
    }
    // ---- layer 2: out = relu(t @ wbT + bb) ----
    bf8 tb[4];
    #pragma unroll
    for (int ks = 0; ks < 4; ++ks)
      tb[ks] = *(const bf8*)(t_w + ((lr * DHc + ks * 32 + l4 * 8) ^ ((lr & 7) << 3)));
    const int node = node0 + lr;
    const bool valid = node < nN;
    int gl = 0, g0 = 0, rep = 0; bool uni = false;
    if (FINAL) {
      gl = batch[valid ? node : (nN - 1)];
      g0 = __shfl(gl, 0);
      uni = __all(gl == g0) && (node0 + 16 <= nN);
      rep = (tile * 8 + wv) & (Rrep - 1);
    }
    #pragma unroll
    for (int jt = 0; jt < 8; ++jt) {
      f4 c = {0.f, 0.f, 0.f, 0.f};
      #pragma unroll
      for (int ks = 0; ks < 4; ++ks) {
        bf8 a = *(const bf8*)(wb_s + (((jt * 16 + lr) * DHc + ks * 32 + l4 * 8) ^ ((lr & 7) << 3)));
        c = __builtin_amdgcn_mfma_f32_16x16x32_bf16(a, tb[ks], c, 0, 0, 0);
      }
      float4 bbv = *(const float4*)(bb + jt * 16 + l4 * 4);
      float o0 = fmaxf(c[0] + bbv.x, 0.f);
      float o1 = fmaxf(c[1] + bbv.y, 0.f);
      float o2 = fmaxf(c[2] + bbv.z, 0.f);
      float o3 = fmaxf(c[3] + bbv.w, 0.f);
      if (!FINAL) {
        if (valid) {
          bf4 hv;
          hv[0] = (short)f2b(o0); hv[1] = (short)f2b(o1);
          hv[2] = (short)f2b(o2); hv[3] = (short)f2b(o3);
          *(bf4*)(hout + (size_t)node * DHc + jt * 16 + l4 * 4) = hv;
        }
      } else {
        if (uni) {
          #pragma unroll
          for (int off = 1; off < 16; off <<= 1) {
            o0 += __shfl_xor(o0, off);
            o1 += __shfl_xor(o1, off);
            o2 += __shfl_xor(o2, off);
            o3 += __shfl_xor(o3, off);
          }
          if (lr == 0) {
            float* dp = sums + ((size_t)rep * Gc + g0) * DHc + jt * 16 + l4 * 4;
            atomicAdd(dp + 0, o0); atomicAdd(dp + 1, o1);
            atomicAdd(dp + 2, o2); atomicAdd(dp + 3, o3);
          }
        } else if (valid) {
          float* dp = sums + ((size_t)rep * Gc + gl) * DHc + jt * 16 + l4 * 4;
          atomicAdd(dp + 0, o0); atomicAdd(dp + 1, o1);
          atomicAdd(dp + 2, o2); atomicAdd(dp + 3, o3);
        }
      }
    }
  }
}

// ---------------- final: reduce replicas, mean, dot with wf ----------------
__global__ __launch_bounds__(128) void pool_final(
    const float* __restrict__ sums, const float* __restrict__ cnts,
    const float* __restrict__ wf, const float* __restrict__ bf,
    float* __restrict__ out)
{
  const int g = blockIdx.x;
  const int j = threadIdx.x;
  float s = 0.f;
  for (int r = 0; r < Rrep; ++r) s += sums[((size_t)r * Gc + g) * DHc + j];
  const float ct = fmaxf(cnts[g], 1.f);
  __shared__ float red[128];
  red[j] = (s / ct) * wf[j];
  __syncthreads();
  for (int off = 64; off > 0; off >>= 1) { if (j < off) red[j] += red[j + off]; __syncthreads(); }
  if (j == 0) out[g] = red[0] + bf[0];
}

extern "C" void kernel_launch(void* const* d_in, const int* in_sizes, int n_in,
                              void* d_out, int out_size, void* d_ws, size_t ws_size,
                              hipStream_t stream) {
  const float* x    = (const float*)d_in[0];
  const int*   ei   = (const int*)d_in[1];
  const float* ea   = (const float*)d_in[2];
  const int*   batch= (const int*)d_in[3];
  const float* ew1  = (const float*)d_in[4];
  const float* eb1  = (const float*)d_in[5];
  const float* w1a  = (const float*)d_in[6];
  const float* b1a  = (const float*)d_in[7];
  const float* w1b  = (const float*)d_in[8];
  const float* b1b  = (const float*)d_in[9];
  const float* ew2  = (const float*)d_in[10];
  const float* eb2  = (const float*)d_in[11];
  const float* w2a  = (const float*)d_in[12];
  const float* b2a  = (const float*)d_in[13];
  const float* w2b  = (const float*)d_in[14];
  const float* b2b  = (const float*)d_in[15];
  const float* wf   = (const float*)d_in[16];
  const float* bf   = (const float*)d_in[17];
  float* out = (float*)d_out;

  const int nN = in_sizes[0] / DINc;
  const int nE = in_sizes[1] / 2;
  const int* srcA = ei;
  const int* dstA = ei + nE;

  char* wsb = (char*)d_ws;
  size_t o = 0;
  u16*   h1b    = (u16*)  (wsb + o); o += (size_t)nN * DHc * 2;
  u16*   xb     = (u16*)  (wsb + o); o += (size_t)nN * DINc * 2;
  float* aggr   = (float*)(wsb + o); o += (size_t)nN * DHc * 4;
  float* sums   = (float*)(wsb + o); o += (size_t)Rrep * Gc * DHc * 4;
  float* cnts   = (float*)(wsb + o); o += (size_t)Gc * 4;
  int*   deg    = (int*)  (wsb + o); o += (size_t)nN * 4;
  int*   cursor = (int*)  (wsb + o); o += (size_t)nN * 4;
  int*   rowptr = (int*)  (wsb + o); o += (size_t)(nN + 1) * 4;
  int*   bsum   = (int*)  (wsb + o); o += (size_t)((nN + SCB - 1) / SCB) * 4; o = (o + 15) & ~(size_t)15;
  int2*  csr    = (int2*) (wsb + o); o += (size_t)nE * 8;
  (void)ws_size; (void)n_in; (void)out_size;

  hipMemsetAsync(sums, 0, (size_t)Rrep * Gc * DHc * 4 + (size_t)Gc * 4, stream);
  hipMemsetAsync(deg, 0, (size_t)nN * 8, stream);

  const int nB = (nN + SCB - 1) / SCB;
  k_cvt<<<1024, 256, 0, stream>>>(x, xb, nN * DINc / 8);
  k_hist<<<1024, 256, 0, stream>>>(dstA, nE, deg);
  k_scan_blk<<<nB, 256, 0, stream>>>(deg, bsum, nN);
  k_scan_fin<<<nB, 256, 0, stream>>>(deg, bsum, rowptr, nN, nB);
  k_fill<<<1024, 256, 0, stream>>>(dstA, srcA, nE, rowptr, cursor, csr);
  k_cnt_bs<<<1, 256, 0, stream>>>(batch, cnts, nN);

  const int nt = (nN + 127) / 128;
  gather_conv<DINc><<<2048, 256, 0, stream>>>(xb, csr, ea, ew1, eb1, rowptr, aggr, nN);
  mlp_mfma<DINc, false><<<256, 512, 0, stream>>>(xb, aggr, w1a, b1a, w1b, b1b,
                                                 h1b, nullptr, nullptr, nN, nt);
  gather_conv<DHc><<<2048, 256, 0, stream>>>(h1b, csr, ea, ew2, eb2, rowptr, aggr, nN);
  mlp_mfma<DHc, true><<<256, 512, 0, stream>>>(h1b, aggr, w2a, b2a, w2b, b2b,
                                               nullptr, batch, sums, nN, nt);
  pool_final<<<Gc, 128, 0, stream>>>(sums, cnts, wf, bf, out);
}

// Round 6
// 677.743 us; speedup vs baseline: 2.4900x; 1.0024x over previous
//
#include <hip/hip_runtime.h>

#define DINc 64
#define DHc  128
#define DEc  16
#define Gc   256
#define Rrep 64
#define SCB  1024

typedef unsigned short u16;
typedef unsigned int   u32;
typedef __attribute__((ext_vector_type(8))) short bf8;
typedef __attribute__((ext_vector_type(4))) short bf4;
typedef __attribute__((ext_vector_type(4))) float f4;

__device__ __forceinline__ u16 f2b(float f) {
  u32 u = __builtin_bit_cast(u32, f);
  u32 r = u + 0x7FFFu + ((u >> 16) & 1u);   // round-to-nearest-even
  return (u16)(r >> 16);
}
__device__ __forceinline__ float b2f(u16 h) {
  u32 u = ((u32)h) << 16;
  return __builtin_bit_cast(float, u);
}

// ---------------- convert fp32 -> bf16 (also used for weight prepack) ----------------
__global__ __launch_bounds__(256) void k_cvt(const float* __restrict__ x,
                                             u16* __restrict__ xb, const int n8) {
  for (int i = blockIdx.x * 256 + threadIdx.x; i < n8; i += gridDim.x * 256) {
    float4 f0 = *(const float4*)(x + (size_t)i * 8);
    float4 f1 = *(const float4*)(x + (size_t)i * 8 + 4);
    bf8 v;
    v[0]=(short)f2b(f0.x); v[1]=(short)f2b(f0.y); v[2]=(short)f2b(f0.z); v[3]=(short)f2b(f0.w);
    v[4]=(short)f2b(f1.x); v[5]=(short)f2b(f1.y); v[6]=(short)f2b(f1.z); v[7]=(short)f2b(f1.w);
    *(bf8*)(xb + (size_t)i * 8) = v;
  }
}

// ---------------- CSR build ----------------
__global__ __launch_bounds__(256) void k_hist(const int* __restrict__ dstA, const int nE,
                                              int* __restrict__ deg) {
  for (int i = blockIdx.x * 256 + threadIdx.x; i < nE; i += gridDim.x * 256)
    atomicAdd(&deg[dstA[i]], 1);
}

__global__ __launch_bounds__(256) void k_scan_blk(const int* __restrict__ deg,
                                                  int* __restrict__ bsum, const int nN) {
  const int b = blockIdx.x, t = threadIdx.x;
  const int i0 = b * SCB + t * 4;
  int s = 0;
  #pragma unroll
  for (int q = 0; q < 4; ++q) { const int i = i0 + q; if (i < nN) s += deg[i]; }
  #pragma unroll
  for (int off = 32; off > 0; off >>= 1) s += __shfl_down(s, off);
  __shared__ int ws[4];
  if ((t & 63) == 0) ws[t >> 6] = s;
  __syncthreads();
  if (t == 0) bsum[b] = ws[0] + ws[1] + ws[2] + ws[3];
}

__global__ __launch_bounds__(256) void k_scan_fin(const int* __restrict__ deg,
                                                  const int* __restrict__ bsum,
                                                  int* __restrict__ rowptr,
                                                  const int nN, const int nB) {
  const int b = blockIdx.x, t = threadIdx.x;
  int p = 0;
  for (int i = t; i < b; i += 256) p += bsum[i];
  #pragma unroll
  for (int off = 32; off > 0; off >>= 1) p += __shfl_down(p, off);
  __shared__ int ws[4];
  __shared__ int sc[256];
  if ((t & 63) == 0) ws[t >> 6] = p;
  const int i0 = b * SCB + t * 4;
  int vals[4]; int s = 0;
  #pragma unroll
  for (int q = 0; q < 4; ++q) { const int i = i0 + q; vals[q] = (i < nN) ? deg[i] : 0; s += vals[q]; }
  sc[t] = s;
  __syncthreads();
  const int boff = ws[0] + ws[1] + ws[2] + ws[3];
  for (int off = 1; off < 256; off <<= 1) {
    int u = (t >= off) ? sc[t - off] : 0;
    __syncthreads();
    sc[t] += u;
    __syncthreads();
  }
  int run = boff + sc[t] - s;
  #pragma unroll
  for (int q = 0; q < 4; ++q) { const int i = i0 + q; if (i < nN) rowptr[i] = run; run += vals[q]; }
  if (b == nB - 1 && t == 255) rowptr[nN] = run;
}

__global__ __launch_bounds__(256) void k_fill(const int* __restrict__ dstA,
                                              const int* __restrict__ srcA, const int nE,
                                              const int* __restrict__ rowptr,
                                              int* __restrict__ cursor, int2* __restrict__ csr) {
  for (int i = blockIdx.x * 256 + threadIdx.x; i < nE; i += gridDim.x * 256) {
    const int d = dstA[i];
    const int pos = atomicAdd(&cursor[d], 1);
    csr[rowptr[d] + pos] = make_int2(i, srcA[i]);
  }
}

// batch sorted: per-graph count via binary search (no atomics)
__global__ __launch_bounds__(256) void k_cnt_bs(const int* __restrict__ batch,
                                                float* __restrict__ cnts, const int nN) {
  const int g = threadIdx.x;
  if (g >= Gc) return;
  int lo = 0, hi = nN;
  while (lo < hi) { int m = (lo + hi) >> 1; if (batch[m] < g) lo = m + 1; else hi = m; }
  int lo2 = lo, hi2 = nN;
  while (lo2 < hi2) { int m = (lo2 + hi2) >> 1; if (batch[m] < g + 1) lo2 = m + 1; else hi2 = m; }
  cnts[g] = (float)(lo2 - lo);
}

// ---------------- gather aggregation ----------------
// per 64-edge chunk: lanes gather their own edge's ea row into wave-private LDS
// (parallel vmem), inner loop broadcasts via ds_read_b128 (in-order) and keeps
// 8 independent x-row loads in flight.
template<int D>
__global__ __launch_bounds__(256) void gather_conv(
    const u16* __restrict__ xin, const int2* __restrict__ csr,
    const float* __restrict__ ea, const float* __restrict__ ew,
    const float* __restrict__ eb, const int* __restrict__ rowptr,
    float* __restrict__ aggr, const int nN)
{
  constexpr int PL = D / 64;
  __shared__ float eas[4][64][16];     // 16KB, wave-private slices
  const int lane = threadIdx.x & 63;
  const int wv   = threadIdx.x >> 6;
  float (*E)[16] = eas[wv];
  float wreg[16 * PL];
  float ebr[PL];
  #pragma unroll
  for (int p = 0; p < PL; ++p) {
    const int d = lane * PL + p;
    ebr[p] = eb[d];
    #pragma unroll
    for (int k = 0; k < 16; ++k) wreg[k * PL + p] = ew[d * 16 + k];
  }
  // contiguous node span per wave (CSR reads sequential)
  const int wgid = blockIdx.x * 4 + wv;
  const int nw   = gridDim.x * 4;
  const int npw  = (nN + nw - 1) / nw;
  const int n0 = wgid * npw, n1 = min(n0 + npw, nN);
  for (int n = n0; n < n1; ++n) {
    const int beg = rowptr[n], end = rowptr[n + 1];
    float acc0 = 0.f, acc1 = 0.f;
    for (int chunk = beg; chunk < end; chunk += 64) {
      const int cnt = min(64, end - chunk);
      int2 es = (lane < cnt) ? csr[chunk + lane] : make_int2(0, 0);
      if (lane < cnt) {
        const float4* ep = (const float4*)(ea + (size_t)es.x * 16);
        float4 e0 = ep[0], e1 = ep[1], e2 = ep[2], e3 = ep[3];
        *(float4*)&E[lane][0]  = e0;
        *(float4*)&E[lane][4]  = e1;
        *(float4*)&E[lane][8]  = e2;
        *(float4*)&E[lane][12] = e3;
      }
      for (int i = 0; i < cnt; i += 8) {
        const int g = min(8, cnt - i);
        u32 xv[8];
        #pragma unroll
        for (int q = 0; q < 8; ++q) {
          if (q < g) {
            const int s = __builtin_amdgcn_readlane(es.y, i + q);
            if (PL == 1) xv[q] = (u32)xin[(size_t)s * 64 + lane];
            else         xv[q] = *(const u32*)(xin + (size_t)s * 128 + lane * 2);
          }
        }
        #pragma unroll
        for (int q = 0; q < 8; ++q) {
          if (q < g) {
            const float* Er = E[i + q];
            float ef[16];
            *(float4*)&ef[0]  = *(const float4*)(Er + 0);
            *(float4*)&ef[4]  = *(const float4*)(Er + 4);
            *(float4*)&ef[8]  = *(const float4*)(Er + 8);
            *(float4*)&ef[12] = *(const float4*)(Er + 12);
            if (PL == 1) {
              float v = ebr[0];
              #pragma unroll
              for (int k = 0; k < 16; ++k) v = fmaf(ef[k], wreg[k], v);
              acc0 += fmaxf(b2f((u16)xv[q]) + v, 0.f);
            } else {
              float v0 = ebr[0], v1 = ebr[1];
              #pragma unroll
              for (int k = 0; k < 16; ++k) {
                v0 = fmaf(ef[k], wreg[k * 2 + 0], v0);
                v1 = fmaf(ef[k], wreg[k * 2 + 1], v1);
              }
              acc0 += fmaxf(b2f((u16)(xv[q] & 0xFFFFu)) + v0, 0.f);
              acc1 += fmaxf(b2f((u16)(xv[q] >> 16)) + v1, 0.f);
            }
          }
        }
      }
    }
    if (PL == 1) aggr[(size_t)n * 64 + lane] = acc0;
    else *(float2*)(aggr + (size_t)n * 128 + lane * 2) = make_float2(acc0, acc1);
  }
}

// ---------------- MFMA node MLP: one wave per 16-node tile ----------------
// Weights prepacked bf16 in global (L2-hot); frags loaded straight to registers.
// LDS only for the layer1->layer2 cross-lane exchange (4KB/wave). No barriers.
template<int IN, bool FINAL>
__global__ __launch_bounds__(512) void mlp_mfma(
    const u16* __restrict__ xin, const float* __restrict__ aggr,
    const u16* __restrict__ waB, const float* __restrict__ ba,
    const u16* __restrict__ wbB, const float* __restrict__ bb,
    u16* __restrict__ hout, const int* __restrict__ batch,
    float* __restrict__ sums, const int nN)
{
  __shared__ u16 t_s[8][16 * DHc];     // 32KB
  const int tid = threadIdx.x;
  const int lane = tid & 63, wv = tid >> 6;
  const int lr = lane & 15, l4 = lane >> 4;
  u16* t_w = t_s[wv];
  const int nT = (nN + 15) >> 4;
  const int gw = blockIdx.x * 8 + wv;
  const int nw = gridDim.x * 8;
  const int rep = gw & (Rrep - 1);
  for (int tile = gw; tile < nT; tile += nw) {
    const int node0 = tile * 16;
    const int n = min(node0 + lr, nN - 1);
    // B-frags: bf16(x + aggr) built in registers
    bf8 bfr[IN / 32];
    #pragma unroll
    for (int ks = 0; ks < IN / 32; ++ks) {
      const int k0 = ks * 32 + l4 * 8;
      bf8 xv = *(const bf8*)(xin + (size_t)n * IN + k0);
      float4 a0 = *(const float4*)(aggr + (size_t)n * IN + k0);
      float4 a1 = *(const float4*)(aggr + (size_t)n * IN + k0 + 4);
      bf8 v;
      v[0] = (short)f2b(b2f((u16)xv[0]) + a0.x);
      v[1] = (short)f2b(b2f((u16)xv[1]) + a0.y);
      v[2] = (short)f2b(b2f((u16)xv[2]) + a0.z);
      v[3] = (short)f2b(b2f((u16)xv[3]) + a0.w);
      v[4] = (short)f2b(b2f((u16)xv[4]) + a1.x);
      v[5] = (short)f2b(b2f((u16)xv[5]) + a1.y);
      v[6] = (short)f2b(b2f((u16)xv[6]) + a1.z);
      v[7] = (short)f2b(b2f((u16)xv[7]) + a1.w);
      bfr[ks] = v;
    }
    // ---- layer 1: t = relu(xa @ waT + ba) ----
    #pragma unroll
    for (int jt = 0; jt < 8; ++jt) {
      f4 c = {0.f, 0.f, 0.f, 0.f};
      #pragma unroll
      for (int ks = 0; ks < IN / 32; ++ks) {
        bf8 a = *(const bf8*)(waB + (size_t)(jt * 16 + lr) * IN + ks * 32 + l4 * 8);
        c = __builtin_amdgcn_mfma_f32_16x16x32_bf16(a, bfr[ks], c, 0, 0, 0);
      }
      float4 bav = *(const float4*)(ba + jt * 16 + l4 * 4);
      bf4 tv;
      tv[0] = (short)f2b(fmaxf(c[0] + bav.x, 0.f));
      tv[1] = (short)f2b(fmaxf(c[1] + bav.y, 0.f));
      tv[2] = (short)f2b(fmaxf(c[2] + bav.z, 0.f));
      tv[3] = (short)f2b(fmaxf(c[3] + bav.w, 0.f));
      *(bf4*)(t_w + ((lr * DHc + jt * 16 + l4 * 4) ^ ((lr & 7) << 3))) = tv;
    }
    // ---- layer 2: out = relu(t @ wbT + bb) ----
    bf8 tb[4];
    #pragma unroll
    for (int ks = 0; ks < 4; ++ks)
      tb[ks] = *(const bf8*)(t_w + ((lr * DHc + ks * 32 + l4 * 8) ^ ((lr & 7) << 3)));
    const int node = node0 + lr;
    const bool valid = node < nN;
    int gl = 0, g0 = 0; bool uni = false;
    if (FINAL) {
      gl = batch[valid ? node : (nN - 1)];
      g0 = __shfl(gl, 0);
      uni = __all(gl == g0) && (node0 + 16 <= nN);
    }
    #pragma unroll
    for (int jt = 0; jt < 8; ++jt) {
      f4 c = {0.f, 0.f, 0.f, 0.f};
      #pragma unroll
      for (int ks = 0; ks < 4; ++ks) {
        bf8 a = *(const bf8*)(wbB + (size_t)(jt * 16 + lr) * DHc + ks * 32 + l4 * 8);
        c = __builtin_amdgcn_mfma_f32_16x16x32_bf16(a, tb[ks], c, 0, 0, 0);
      }
      float4 bbv = *(const float4*)(bb + jt * 16 + l4 * 4);
      float o0 = fmaxf(c[0] + bbv.x, 0.f);
      float o1 = fmaxf(c[1] + bbv.y, 0.f);
      float o2 = fmaxf(c[2] + bbv.z, 0.f);
      float o3 = fmaxf(c[3] + bbv.w, 0.f);
      if (!FINAL) {
        if (valid) {
          bf4 hv;
          hv[0] = (short)f2b(o0); hv[1] = (short)f2b(o1);
          hv[2] = (short)f2b(o2); hv[3] = (short)f2b(o3);
          *(bf4*)(hout + (size_t)node * DHc + jt * 16 + l4 * 4) = hv;
        }
      } else {
        if (uni) {
          #pragma unroll
          for (int off = 1; off < 16; off <<= 1) {
            o0 += __shfl_xor(o0, off);
            o1 += __shfl_xor(o1, off);
            o2 += __shfl_xor(o2, off);
            o3 += __shfl_xor(o3, off);
          }
          if (lr == 0) {
            float* dp = sums + ((size_t)rep * Gc + g0) * DHc + jt * 16 + l4 * 4;
            atomicAdd(dp + 0, o0); atomicAdd(dp + 1, o1);
            atomicAdd(dp + 2, o2); atomicAdd(dp + 3, o3);
          }
        } else if (valid) {
          float* dp = sums + ((size_t)rep * Gc + gl) * DHc + jt * 16 + l4 * 4;
          atomicAdd(dp + 0, o0); atomicAdd(dp + 1, o1);
          atomicAdd(dp + 2, o2); atomicAdd(dp + 3, o3);
        }
      }
    }
  }
}

// ---------------- final: reduce replicas, mean, dot with wf ----------------
__global__ __launch_bounds__(128) void pool_final(
    const float* __restrict__ sums, const float* __restrict__ cnts,
    const float* __restrict__ wf, const float* __restrict__ bf,
    float* __restrict__ out)
{
  const int g = blockIdx.x;
  const int j = threadIdx.x;
  float s = 0.f;
  for (int r = 0; r < Rrep; ++r) s += sums[((size_t)r * Gc + g) * DHc + j];
  const float ct = fmaxf(cnts[g], 1.f);
  __shared__ float red[128];
  red[j] = (s / ct) * wf[j];
  __syncthreads();
  for (int off = 64; off > 0; off >>= 1) { if (j < off) red[j] += red[j + off]; __syncthreads(); }
  if (j == 0) out[g] = red[0] + bf[0];
}

extern "C" void kernel_launch(void* const* d_in, const int* in_sizes, int n_in,
                              void* d_out, int out_size, void* d_ws, size_t ws_size,
                              hipStream_t stream) {
  const float* x    = (const float*)d_in[0];
  const int*   ei   = (const int*)d_in[1];
  const float* ea   = (const float*)d_in[2];
  const int*   batch= (const int*)d_in[3];
  const float* ew1  = (const float*)d_in[4];
  const float* eb1  = (const float*)d_in[5];
  const float* w1a  = (const float*)d_in[6];
  const float* b1a  = (const float*)d_in[7];
  const float* w1b  = (const float*)d_in[8];
  const float* b1b  = (const float*)d_in[9];
  const float* ew2  = (const float*)d_in[10];
  const float* eb2  = (const float*)d_in[11];
  const float* w2a  = (const float*)d_in[12];
  const float* b2a  = (const float*)d_in[13];
  const float* w2b  = (const float*)d_in[14];
  const float* b2b  = (const float*)d_in[15];
  const float* wf   = (const float*)d_in[16];
  const float* bf   = (const float*)d_in[17];
  float* out = (float*)d_out;

  const int nN = in_sizes[0] / DINc;
  const int nE = in_sizes[1] / 2;
  const int* srcA = ei;
  const int* dstA = ei + nE;

  char* wsb = (char*)d_ws;
  size_t o = 0;
  u16*   h1b    = (u16*)  (wsb + o); o += (size_t)nN * DHc * 2;
  u16*   xb     = (u16*)  (wsb + o); o += (size_t)nN * DINc * 2;
  float* aggr   = (float*)(wsb + o); o += (size_t)nN * DHc * 4;
  float* sums   = (float*)(wsb + o); o += (size_t)Rrep * Gc * DHc * 4;
  float* cnts   = (float*)(wsb + o); o += (size_t)Gc * 4;
  int*   deg    = (int*)  (wsb + o); o += (size_t)nN * 4;
  int*   cursor = (int*)  (wsb + o); o += (size_t)nN * 4;
  int*   rowptr = (int*)  (wsb + o); o += (size_t)(nN + 1) * 4;
  int*   bsum   = (int*)  (wsb + o); o += (size_t)((nN + SCB - 1) / SCB) * 4; o = (o + 15) & ~(size_t)15;
  int2*  csr    = (int2*) (wsb + o); o += (size_t)nE * 8;
  u16*   w1ab   = (u16*)  (wsb + o); o += (size_t)DHc * DINc * 2;
  u16*   w1bb   = (u16*)  (wsb + o); o += (size_t)DHc * DHc * 2;
  u16*   w2ab   = (u16*)  (wsb + o); o += (size_t)DHc * DHc * 2;
  u16*   w2bb   = (u16*)  (wsb + o); o += (size_t)DHc * DHc * 2;
  (void)ws_size; (void)n_in; (void)out_size;

  hipMemsetAsync(sums, 0, (size_t)Rrep * Gc * DHc * 4 + (size_t)Gc * 4, stream);
  hipMemsetAsync(deg, 0, (size_t)nN * 8, stream);

  const int nB = (nN + SCB - 1) / SCB;
  k_cvt<<<1024, 256, 0, stream>>>(x, xb, nN * DINc / 8);
  k_cvt<<<4, 256, 0, stream>>>(w1a, w1ab, DHc * DINc / 8);
  k_cvt<<<8, 256, 0, stream>>>(w1b, w1bb, DHc * DHc / 8);
  k_cvt<<<8, 256, 0, stream>>>(w2a, w2ab, DHc * DHc / 8);
  k_cvt<<<8, 256, 0, stream>>>(w2b, w2bb, DHc * DHc / 8);
  k_hist<<<1024, 256, 0, stream>>>(dstA, nE, deg);
  k_scan_blk<<<nB, 256, 0, stream>>>(deg, bsum, nN);
  k_scan_fin<<<nB, 256, 0, stream>>>(deg, bsum, rowptr, nN, nB);
  k_fill<<<1024, 256, 0, stream>>>(dstA, srcA, nE, rowptr, cursor, csr);
  k_cnt_bs<<<1, 256, 0, stream>>>(batch, cnts, nN);

  const int nT = (nN + 15) / 16;
  const int mgrid = (nT + 7) / 8;
  gather_conv<DINc><<<2048, 256, 0, stream>>>(xb, csr, ea, ew1, eb1, rowptr, aggr, nN);
  mlp_mfma<DINc, false><<<mgrid, 512, 0, stream>>>(xb, aggr, w1ab, b1a, w1bb, b1b,
                                                   h1b, nullptr, nullptr, nN);
  gather_conv<DHc><<<2048, 256, 0, stream>>>(h1b, csr, ea, ew2, eb2, rowptr, aggr, nN);
  mlp_mfma<DHc, true><<<mgrid, 512, 0, stream>>>(h1b, aggr, w2ab, b2a, w2bb, b2b,
                                                 nullptr, batch, sums, nN);
  pool_final<<<Gc, 128, 0, stream>>>(sums, cnts, wf, bf, out);
}

// Round 7
// 577.949 us; speedup vs baseline: 2.9200x; 1.1727x over previous
//
#include <hip/hip_runtime.h>

#define DINc 64
#define DHc  128
#define DEc  16
#define Gc   256
#define Rrep 64
#define SCB  1024

typedef unsigned short u16;
typedef unsigned int   u32;
typedef __attribute__((ext_vector_type(8))) short bf8;
typedef __attribute__((ext_vector_type(4))) short bf4;
typedef __attribute__((ext_vector_type(4))) float f4;

__device__ __forceinline__ u16 f2b(float f) {
  u32 u = __builtin_bit_cast(u32, f);
  u32 r = u + 0x7FFFu + ((u >> 16) & 1u);   // round-to-nearest-even
  return (u16)(r >> 16);
}
__device__ __forceinline__ float b2f(u16 h) {
  u32 u = ((u32)h) << 16;
  return __builtin_bit_cast(float, u);
}

// ---------------- convert fp32 -> bf16 (also used for weight prepack) ----------------
__global__ __launch_bounds__(256) void k_cvt(const float* __restrict__ x,
                                             u16* __restrict__ xb, const int n8) {
  for (int i = blockIdx.x * 256 + threadIdx.x; i < n8; i += gridDim.x * 256) {
    float4 f0 = *(const float4*)(x + (size_t)i * 8);
    float4 f1 = *(const float4*)(x + (size_t)i * 8 + 4);
    bf8 v;
    v[0]=(short)f2b(f0.x); v[1]=(short)f2b(f0.y); v[2]=(short)f2b(f0.z); v[3]=(short)f2b(f0.w);
    v[4]=(short)f2b(f1.x); v[5]=(short)f2b(f1.y); v[6]=(short)f2b(f1.z); v[7]=(short)f2b(f1.w);
    *(bf8*)(xb + (size_t)i * 8) = v;
  }
}

// ---------------- CSR build ----------------
__global__ __launch_bounds__(256) void k_hist(const int* __restrict__ dstA, const int nE,
                                              int* __restrict__ deg) {
  for (int i = blockIdx.x * 256 + threadIdx.x; i < nE; i += gridDim.x * 256)
    atomicAdd(&deg[dstA[i]], 1);
}

__global__ __launch_bounds__(256) void k_scan_blk(const int* __restrict__ deg,
                                                  int* __restrict__ bsum, const int nN) {
  const int b = blockIdx.x, t = threadIdx.x;
  const int i0 = b * SCB + t * 4;
  int s = 0;
  #pragma unroll
  for (int q = 0; q < 4; ++q) { const int i = i0 + q; if (i < nN) s += deg[i]; }
  #pragma unroll
  for (int off = 32; off > 0; off >>= 1) s += __shfl_down(s, off);
  __shared__ int ws[4];
  if ((t & 63) == 0) ws[t >> 6] = s;
  __syncthreads();
  if (t == 0) bsum[b] = ws[0] + ws[1] + ws[2] + ws[3];
}

__global__ __launch_bounds__(256) void k_scan_fin(const int* __restrict__ deg,
                                                  const int* __restrict__ bsum,
                                                  int* __restrict__ rowptr,
                                                  const int nN, const int nB) {
  const int b = blockIdx.x, t = threadIdx.x;
  int p = 0;
  for (int i = t; i < b; i += 256) p += bsum[i];
  #pragma unroll
  for (int off = 32; off > 0; off >>= 1) p += __shfl_down(p, off);
  __shared__ int ws[4];
  __shared__ int sc[256];
  if ((t & 63) == 0) ws[t >> 6] = p;
  const int i0 = b * SCB + t * 4;
  int vals[4]; int s = 0;
  #pragma unroll
  for (int q = 0; q < 4; ++q) { const int i = i0 + q; vals[q] = (i < nN) ? deg[i] : 0; s += vals[q]; }
  sc[t] = s;
  __syncthreads();
  const int boff = ws[0] + ws[1] + ws[2] + ws[3];
  for (int off = 1; off < 256; off <<= 1) {
    int u = (t >= off) ? sc[t - off] : 0;
    __syncthreads();
    sc[t] += u;
    __syncthreads();
  }
  int run = boff + sc[t] - s;
  #pragma unroll
  for (int q = 0; q < 4; ++q) { const int i = i0 + q; if (i < nN) rowptr[i] = run; run += vals[q]; }
  if (b == nB - 1 && t == 255) rowptr[nN] = run;
}

__global__ __launch_bounds__(256) void k_fill(const int* __restrict__ dstA,
                                              const int* __restrict__ srcA, const int nE,
                                              const int* __restrict__ rowptr,
                                              int* __restrict__ cursor, int2* __restrict__ csr) {
  for (int i = blockIdx.x * 256 + threadIdx.x; i < nE; i += gridDim.x * 256) {
    const int d = dstA[i];
    const int pos = atomicAdd(&cursor[d], 1);
    csr[rowptr[d] + pos] = make_int2(i, srcA[i]);
  }
}

// batch sorted: per-graph count via binary search (no atomics)
__global__ __launch_bounds__(256) void k_cnt_bs(const int* __restrict__ batch,
                                                float* __restrict__ cnts, const int nN) {
  const int g = threadIdx.x;
  if (g >= Gc) return;
  int lo = 0, hi = nN;
  while (lo < hi) { int m = (lo + hi) >> 1; if (batch[m] < g) lo = m + 1; else hi = m; }
  int lo2 = lo, hi2 = nN;
  while (lo2 < hi2) { int m = (lo2 + hi2) >> 1; if (batch[m] < g + 1) lo2 = m + 1; else hi2 = m; }
  cnts[g] = (float)(lo2 - lo);
}

// ---------------- gather aggregation (unchanged from R6) ----------------
template<int D>
__global__ __launch_bounds__(256) void gather_conv(
    const u16* __restrict__ xin, const int2* __restrict__ csr,
    const float* __restrict__ ea, const float* __restrict__ ew,
    const float* __restrict__ eb, const int* __restrict__ rowptr,
    float* __restrict__ aggr, const int nN)
{
  constexpr int PL = D / 64;
  __shared__ float eas[4][64][16];     // 16KB, wave-private slices
  const int lane = threadIdx.x & 63;
  const int wv   = threadIdx.x >> 6;
  float (*E)[16] = eas[wv];
  float wreg[16 * PL];
  float ebr[PL];
  #pragma unroll
  for (int p = 0; p < PL; ++p) {
    const int d = lane * PL + p;
    ebr[p] = eb[d];
    #pragma unroll
    for (int k = 0; k < 16; ++k) wreg[k * PL + p] = ew[d * 16 + k];
  }
  const int wgid = blockIdx.x * 4 + wv;
  const int nw   = gridDim.x * 4;
  const int npw  = (nN + nw - 1) / nw;
  const int n0 = wgid * npw, n1 = min(n0 + npw, nN);
  for (int n = n0; n < n1; ++n) {
    const int beg = rowptr[n], end = rowptr[n + 1];
    float acc0 = 0.f, acc1 = 0.f;
    for (int chunk = beg; chunk < end; chunk += 64) {
      const int cnt = min(64, end - chunk);
      int2 es = (lane < cnt) ? csr[chunk + lane] : make_int2(0, 0);
      if (lane < cnt) {
        const float4* ep = (const float4*)(ea + (size_t)es.x * 16);
        float4 e0 = ep[0], e1 = ep[1], e2 = ep[2], e3 = ep[3];
        *(float4*)&E[lane][0]  = e0;
        *(float4*)&E[lane][4]  = e1;
        *(float4*)&E[lane][8]  = e2;
        *(float4*)&E[lane][12] = e3;
      }
      for (int i = 0; i < cnt; i += 8) {
        const int g = min(8, cnt - i);
        u32 xv[8];
        #pragma unroll
        for (int q = 0; q < 8; ++q) {
          if (q < g) {
            const int s = __builtin_amdgcn_readlane(es.y, i + q);
            if (PL == 1) xv[q] = (u32)xin[(size_t)s * 64 + lane];
            else         xv[q] = *(const u32*)(xin + (size_t)s * 128 + lane * 2);
          }
        }
        #pragma unroll
        for (int q = 0; q < 8; ++q) {
          if (q < g) {
            const float* Er = E[i + q];
            float ef[16];
            *(float4*)&ef[0]  = *(const float4*)(Er + 0);
            *(float4*)&ef[4]  = *(const float4*)(Er + 4);
            *(float4*)&ef[8]  = *(const float4*)(Er + 8);
            *(float4*)&ef[12] = *(const float4*)(Er + 12);
            if (PL == 1) {
              float v = ebr[0];
              #pragma unroll
              for (int k = 0; k < 16; ++k) v = fmaf(ef[k], wreg[k], v);
              acc0 += fmaxf(b2f((u16)xv[q]) + v, 0.f);
            } else {
              float v0 = ebr[0], v1 = ebr[1];
              #pragma unroll
              for (int k = 0; k < 16; ++k) {
                v0 = fmaf(ef[k], wreg[k * 2 + 0], v0);
                v1 = fmaf(ef[k], wreg[k * 2 + 1], v1);
              }
              acc0 += fmaxf(b2f((u16)(xv[q] & 0xFFFFu)) + v0, 0.f);
              acc1 += fmaxf(b2f((u16)(xv[q] >> 16)) + v1, 0.f);
            }
          }
        }
      }
    }
    if (PL == 1) aggr[(size_t)n * 64 + lane] = acc0;
    else *(float2*)(aggr + (size_t)n * 128 + lane * 2) = make_float2(acc0, acc1);
  }
}

// ---------------- MLP layer 1: t = relu((x+aggr) @ waT + ba) ----------------
// 4 waves/block, 16 nodes/wave; only wa (16/32KB) in LDS -> 4-5 blocks/CU.
template<int IN>
__global__ __launch_bounds__(256) void k_l1(
    const u16* __restrict__ xin, const float* __restrict__ aggr,
    const u16* __restrict__ waB, const float* __restrict__ ba,
    u16* __restrict__ tout, const int nN)
{
  __shared__ u16 wa_s[DHc * IN];
  __shared__ float ba_s[DHc];
  const int tid = threadIdx.x;
  constexpr int INC = IN / 8;
  for (int c = tid; c < DHc * INC; c += 256) {
    const int row = c / INC, kc = (c % INC) * 8;
    bf8 v = *(const bf8*)(waB + (size_t)row * IN + kc);
    *(bf8*)(wa_s + ((row * IN + kc) ^ ((row & 7) << 3))) = v;
  }
  if (tid < DHc) ba_s[tid] = ba[tid];
  __syncthreads();
  const int lane = tid & 63, wv = tid >> 6;
  const int lr = lane & 15, l4 = lane >> 4;
  const int nT = (nN + 15) >> 4;
  for (int tile = blockIdx.x * 4 + wv; tile < nT; tile += gridDim.x * 4) {
    const int node = tile * 16 + lr;
    const int n = min(node, nN - 1);
    bf8 bfr[IN / 32];
    #pragma unroll
    for (int ks = 0; ks < IN / 32; ++ks) {
      const int k0 = ks * 32 + l4 * 8;
      bf8 xv = *(const bf8*)(xin + (size_t)n * IN + k0);
      float4 a0 = *(const float4*)(aggr + (size_t)n * IN + k0);
      float4 a1 = *(const float4*)(aggr + (size_t)n * IN + k0 + 4);
      bf8 v;
      v[0] = (short)f2b(b2f((u16)xv[0]) + a0.x);
      v[1] = (short)f2b(b2f((u16)xv[1]) + a0.y);
      v[2] = (short)f2b(b2f((u16)xv[2]) + a0.z);
      v[3] = (short)f2b(b2f((u16)xv[3]) + a0.w);
      v[4] = (short)f2b(b2f((u16)xv[4]) + a1.x);
      v[5] = (short)f2b(b2f((u16)xv[5]) + a1.y);
      v[6] = (short)f2b(b2f((u16)xv[6]) + a1.z);
      v[7] = (short)f2b(b2f((u16)xv[7]) + a1.w);
      bfr[ks] = v;
    }
    const bool valid = node < nN;
    #pragma unroll
    for (int jt = 0; jt < 8; ++jt) {
      f4 c = {0.f, 0.f, 0.f, 0.f};
      #pragma unroll
      for (int ks = 0; ks < IN / 32; ++ks) {
        bf8 a = *(const bf8*)(wa_s + (((jt * 16 + lr) * IN + ks * 32 + l4 * 8) ^ ((lr & 7) << 3)));
        c = __builtin_amdgcn_mfma_f32_16x16x32_bf16(a, bfr[ks], c, 0, 0, 0);
      }
      if (valid) {
        float4 bav = *(const float4*)(ba_s + jt * 16 + l4 * 4);
        bf4 tv;
        tv[0] = (short)f2b(fmaxf(c[0] + bav.x, 0.f));
        tv[1] = (short)f2b(fmaxf(c[1] + bav.y, 0.f));
        tv[2] = (short)f2b(fmaxf(c[2] + bav.z, 0.f));
        tv[3] = (short)f2b(fmaxf(c[3] + bav.w, 0.f));
        *(bf4*)(tout + (size_t)node * DHc + jt * 16 + l4 * 4) = tv;
      }
    }
  }
}

// ---------------- MLP layer 2: out = relu(t @ wbT + bb) ----------------
template<bool FINAL>
__global__ __launch_bounds__(256) void k_l2(
    const u16* __restrict__ tin, const u16* __restrict__ wbB,
    const float* __restrict__ bb, u16* __restrict__ hout,
    const int* __restrict__ batch, float* __restrict__ sums, const int nN)
{
  __shared__ u16 wb_s[DHc * DHc];
  __shared__ float bb_s[DHc];
  const int tid = threadIdx.x;
  for (int c = tid; c < DHc * 16; c += 256) {
    const int row = c >> 4, kc = (c & 15) * 8;
    bf8 v = *(const bf8*)(wbB + (size_t)row * DHc + kc);
    *(bf8*)(wb_s + ((row * DHc + kc) ^ ((row & 7) << 3))) = v;
  }
  if (tid < DHc) bb_s[tid] = bb[tid];
  __syncthreads();
  const int lane = tid & 63, wv = tid >> 6;
  const int lr = lane & 15, l4 = lane >> 4;
  const int nT = (nN + 15) >> 4;
  const int gw0 = blockIdx.x * 4 + wv;
  const int rep = gw0 & (Rrep - 1);
  for (int tile = gw0; tile < nT; tile += gridDim.x * 4) {
    const int node0 = tile * 16;
    const int node = node0 + lr;
    const int n = min(node, nN - 1);
    bf8 tb[4];
    #pragma unroll
    for (int ks = 0; ks < 4; ++ks)
      tb[ks] = *(const bf8*)(tin + (size_t)n * DHc + ks * 32 + l4 * 8);
    const bool valid = node < nN;
    int gl = 0, g0 = 0; bool uni = false;
    if (FINAL) {
      gl = batch[n];
      g0 = __shfl(gl, 0);
      uni = __all(gl == g0) && (node0 + 16 <= nN);
    }
    #pragma unroll
    for (int jt = 0; jt < 8; ++jt) {
      f4 c = {0.f, 0.f, 0.f, 0.f};
      #pragma unroll
      for (int ks = 0; ks < 4; ++ks) {
        bf8 a = *(const bf8*)(wb_s + (((jt * 16 + lr) * DHc + ks * 32 + l4 * 8) ^ ((lr & 7) << 3)));
        c = __builtin_amdgcn_mfma_f32_16x16x32_bf16(a, tb[ks], c, 0, 0, 0);
      }
      float4 bbv = *(const float4*)(bb_s + jt * 16 + l4 * 4);
      float o0 = fmaxf(c[0] + bbv.x, 0.f);
      float o1 = fmaxf(c[1] + bbv.y, 0.f);
      float o2 = fmaxf(c[2] + bbv.z, 0.f);
      float o3 = fmaxf(c[3] + bbv.w, 0.f);
      if (!FINAL) {
        if (valid) {
          bf4 hv;
          hv[0] = (short)f2b(o0); hv[1] = (short)f2b(o1);
          hv[2] = (short)f2b(o2); hv[3] = (short)f2b(o3);
          *(bf4*)(hout + (size_t)node * DHc + jt * 16 + l4 * 4) = hv;
        }
      } else {
        if (uni) {
          #pragma unroll
          for (int off = 1; off < 16; off <<= 1) {
            o0 += __shfl_xor(o0, off);
            o1 += __shfl_xor(o1, off);
            o2 += __shfl_xor(o2, off);
            o3 += __shfl_xor(o3, off);
          }
          if (lr == 0) {
            float* dp = sums + ((size_t)rep * Gc + g0) * DHc + jt * 16 + l4 * 4;
            atomicAdd(dp + 0, o0); atomicAdd(dp + 1, o1);
            atomicAdd(dp + 2, o2); atomicAdd(dp + 3, o3);
          }
        } else if (valid) {
          float* dp = sums + ((size_t)rep * Gc + gl) * DHc + jt * 16 + l4 * 4;
          atomicAdd(dp + 0, o0); atomicAdd(dp + 1, o1);
          atomicAdd(dp + 2, o2); atomicAdd(dp + 3, o3);
        }
      }
    }
  }
}

// ---------------- final: reduce replicas, mean, dot with wf ----------------
__global__ __launch_bounds__(128) void pool_final(
    const float* __restrict__ sums, const float* __restrict__ cnts,
    const float* __restrict__ wf, const float* __restrict__ bf,
    float* __restrict__ out)
{
  const int g = blockIdx.x;
  const int j = threadIdx.x;
  float s = 0.f;
  for (int r = 0; r < Rrep; ++r) s += sums[((size_t)r * Gc + g) * DHc + j];
  const float ct = fmaxf(cnts[g], 1.f);
  __shared__ float red[128];
  red[j] = (s / ct) * wf[j];
  __syncthreads();
  for (int off = 64; off > 0; off >>= 1) { if (j < off) red[j] += red[j + off]; __syncthreads(); }
  if (j == 0) out[g] = red[0] + bf[0];
}

extern "C" void kernel_launch(void* const* d_in, const int* in_sizes, int n_in,
                              void* d_out, int out_size, void* d_ws, size_t ws_size,
                              hipStream_t stream) {
  const float* x    = (const float*)d_in[0];
  const int*   ei   = (const int*)d_in[1];
  const float* ea   = (const float*)d_in[2];
  const int*   batch= (const int*)d_in[3];
  const float* ew1  = (const float*)d_in[4];
  const float* eb1  = (const float*)d_in[5];
  const float* w1a  = (const float*)d_in[6];
  const float* b1a  = (const float*)d_in[7];
  const float* w1b  = (const float*)d_in[8];
  const float* b1b  = (const float*)d_in[9];
  const float* ew2  = (const float*)d_in[10];
  const float* eb2  = (const float*)d_in[11];
  const float* w2a  = (const float*)d_in[12];
  const float* b2a  = (const float*)d_in[13];
  const float* w2b  = (const float*)d_in[14];
  const float* b2b  = (const float*)d_in[15];
  const float* wf   = (const float*)d_in[16];
  const float* bf   = (const float*)d_in[17];
  float* out = (float*)d_out;

  const int nN = in_sizes[0] / DINc;
  const int nE = in_sizes[1] / 2;
  const int* srcA = ei;
  const int* dstA = ei + nE;

  char* wsb = (char*)d_ws;
  size_t o = 0;
  u16*   h1b    = (u16*)  (wsb + o); o += (size_t)nN * DHc * 2;
  u16*   xb     = (u16*)  (wsb + o); o += (size_t)nN * DINc * 2;
  u16*   tbuf   = (u16*)  (wsb + o); o += (size_t)nN * DHc * 2;
  float* aggr   = (float*)(wsb + o); o += (size_t)nN * DHc * 4;
  float* sums   = (float*)(wsb + o); o += (size_t)Rrep * Gc * DHc * 4;
  float* cnts   = (float*)(wsb + o); o += (size_t)Gc * 4;
  int*   deg    = (int*)  (wsb + o); o += (size_t)nN * 4;
  int*   cursor = (int*)  (wsb + o); o += (size_t)nN * 4;
  int*   rowptr = (int*)  (wsb + o); o += (size_t)(nN + 1) * 4;
  int*   bsum   = (int*)  (wsb + o); o += (size_t)((nN + SCB - 1) / SCB) * 4; o = (o + 15) & ~(size_t)15;
  int2*  csr    = (int2*) (wsb + o); o += (size_t)nE * 8;
  u16*   w1ab   = (u16*)  (wsb + o); o += (size_t)DHc * DINc * 2;
  u16*   w1bb   = (u16*)  (wsb + o); o += (size_t)DHc * DHc * 2;
  u16*   w2ab   = (u16*)  (wsb + o); o += (size_t)DHc * DHc * 2;
  u16*   w2bb   = (u16*)  (wsb + o); o += (size_t)DHc * DHc * 2;
  (void)ws_size; (void)n_in; (void)out_size;

  hipMemsetAsync(sums, 0, (size_t)Rrep * Gc * DHc * 4 + (size_t)Gc * 4, stream);
  hipMemsetAsync(deg, 0, (size_t)nN * 8, stream);

  const int nB = (nN + SCB - 1) / SCB;
  k_cvt<<<1024, 256, 0, stream>>>(x, xb, nN * DINc / 8);
  k_cvt<<<4, 256, 0, stream>>>(w1a, w1ab, DHc * DINc / 8);
  k_cvt<<<8, 256, 0, stream>>>(w1b, w1bb, DHc * DHc / 8);
  k_cvt<<<8, 256, 0, stream>>>(w2a, w2ab, DHc * DHc / 8);
  k_cvt<<<8, 256, 0, stream>>>(w2b, w2bb, DHc * DHc / 8);
  k_hist<<<1024, 256, 0, stream>>>(dstA, nE, deg);
  k_scan_blk<<<nB, 256, 0, stream>>>(deg, bsum, nN);
  k_scan_fin<<<nB, 256, 0, stream>>>(deg, bsum, rowptr, nN, nB);
  k_fill<<<1024, 256, 0, stream>>>(dstA, srcA, nE, rowptr, cursor, csr);
  k_cnt_bs<<<1, 256, 0, stream>>>(batch, cnts, nN);

  const int nT = (nN + 15) / 16;
  const int mg = (nT + 3) / 4;
  gather_conv<DINc><<<2048, 256, 0, stream>>>(xb, csr, ea, ew1, eb1, rowptr, aggr, nN);
  k_l1<DINc><<<mg, 256, 0, stream>>>(xb, aggr, w1ab, b1a, tbuf, nN);
  k_l2<false><<<mg, 256, 0, stream>>>(tbuf, w1bb, b1b, h1b, nullptr, nullptr, nN);
  gather_conv<DHc><<<2048, 256, 0, stream>>>(h1b, csr, ea, ew2, eb2, rowptr, aggr, nN);
  k_l1<DHc><<<mg, 256, 0, stream>>>(h1b, aggr, w2ab, b2a, tbuf, nN);
  k_l2<true><<<mg, 256, 0, stream>>>(tbuf, w2bb, b2b, nullptr, batch, sums, nN);
  pool_final<<<Gc, 128, 0, stream>>>(sums, cnts, wf, bf, out);
}